// Round 5
// baseline (1246.637 us; speedup 1.0000x reference)
//
#include <hip/hip_runtime.h>

typedef _Float16 half8 __attribute__((ext_vector_type(8)));
typedef float f32x4 __attribute__((ext_vector_type(4)));
typedef unsigned long long ull;

// ---- ws layout (byte offsets) ----
#define OFF_WTH   0u          // WtH  fp16 [1024][320] = 655360
#define OFF_WCH   655360u     // WcH  fp16 [128][256]  = 65536
#define OFF_BIASG 720896u     // biasG f32 [1024]      = 4096
#define OFF_WX    724992u     // Wx   f32  [768][64]   = 196608
#define OFF_XH    921600u     // xH   fp16 [1024][64][64] = 8388608
#define OFF_HCF   9310208u    // hcF  f32  [2][32][64][128] = 2097152
#define OFF_FLAGS 11407360u   // rowflag int[64]
// total ≈ 11.4 MB

// ---------------- coherent helpers (LLC-performed, r3/r4-proven) ----------
__device__ __forceinline__ int ldrlx(const int* p) {
    return __hip_atomic_load(p, __ATOMIC_RELAXED, __HIP_MEMORY_SCOPE_AGENT);
}
__device__ __forceinline__ ull ald64(const void* p) {
    return __hip_atomic_load((const ull*)p, __ATOMIC_RELAXED, __HIP_MEMORY_SCOPE_AGENT);
}
__device__ __forceinline__ void ast64(void* p, ull v) {
    __hip_atomic_store((ull*)p, v, __ATOMIC_RELAXED, __HIP_MEMORY_SCOPE_AGENT);
}
__device__ __forceinline__ float2 up64(ull u) {
    union { ull u; float f[2]; } v; v.u = u;
    return make_float2(v.f[0], v.f[1]);
}

// ---------------- prep kernels (r4-proven) ----------------
__global__ __launch_bounds__(256) void k_build_wx(
    const float* __restrict__ W_ih, const float* __restrict__ We,
    float* __restrict__ Wx)
{
    __shared__ float WeS[128][64];
    const int tid = threadIdx.x;
    #pragma unroll
    for (int q = 0; q < 8; ++q) {
        int p = q*256 + tid;
        int e = p >> 4, k4 = p & 15;
        *(float4*)&WeS[e][k4*4] = *(const float4*)&We[e*64 + k4*4];
    }
    __syncthreads();
    int idx = blockIdx.x*256 + tid;     // 49152 -> 192 blocks
    int r = idx >> 6, k = idx & 63;
    float acc = 0.f;
    #pragma unroll 4
    for (int e = 0; e < 128; ++e) acc = fmaf(W_ih[r*128 + e], WeS[e][k], acc);
    Wx[idx] = acc;
}

__global__ __launch_bounds__(256) void k_prep_wt(
    const float* __restrict__ Wx, const float* __restrict__ W_hh,
    _Float16* __restrict__ WtH)
{
    int row = blockIdx.x;               // 1024
    int g = row >> 8, c = row & 255;
    for (int k = threadIdx.x; k < 320; k += 256) {
        float v;
        if (k < 64) v = (g == 3) ? 0.f : Wx[(g*256 + c)*64 + k];
        else if (g == 2) v = 0.f;
        else { int rr = (g == 3) ? (512 + c) : (g*256 + c); v = W_hh[rr*256 + (k - 64)]; }
        WtH[row*320 + k] = (_Float16)v;
    }
}

__global__ __launch_bounds__(256) void k_prep_bias(
    const float* __restrict__ b_ih, const float* __restrict__ b_hh,
    const float* __restrict__ W_ih, const float* __restrict__ be,
    float* __restrict__ biasG)
{
    int row = blockIdx.x*256 + threadIdx.x;   // 1024
    int g = row >> 8, c = row & 255;
    float v;
    if (g < 3) {
        int r = g*256 + c;
        float bx = b_ih[r];
        #pragma unroll 4
        for (int e = 0; e < 128; ++e) bx = fmaf(W_ih[r*128 + e], be[e], bx);
        v = (g == 0) ? bx + b_hh[c] : (g == 1) ? bx + b_hh[256 + c] : bx;
    } else v = b_hh[512 + c];
    biasG[row] = v;
}

__global__ __launch_bounds__(256) void k_prep_wc(
    const float* __restrict__ Wc, _Float16* __restrict__ WcH)
{
    int i4 = (blockIdx.x*256 + threadIdx.x)*4;   // 32768 -> 32 blocks
    float4 v = *(const float4*)&Wc[i4];
    WcH[i4+0] = (_Float16)v.x; WcH[i4+1] = (_Float16)v.y;
    WcH[i4+2] = (_Float16)v.z; WcH[i4+3] = (_Float16)v.w;
}

__global__ __launch_bounds__(256) void k_prep_x(
    const float* __restrict__ x, _Float16* __restrict__ xH)
{
    int cell = blockIdx.x;              // 1024
    int i = cell >> 5, j = cell & 31;
    int b = threadIdx.x >> 2, k16 = (threadIdx.x & 3)*16;
    const float* src = &x[((b*32 + i)*32 + j)*64 + k16];
    _Float16* dst = &xH[((ull)cell*64 + b)*64 + k16];
    #pragma unroll
    for (int kk = 0; kk < 16; kk += 4) {
        float4 v = *(const float4*)&src[kk];
        dst[kk+0] = (_Float16)v.x; dst[kk+1] = (_Float16)v.y;
        dst[kk+2] = (_Float16)v.z; dst[kk+3] = (_Float16)v.w;
    }
}

// ---------------- persistent 2D-GRU: batch-split, weights-in-registers ----
// 64 WGs x 512 thr. WG (i = blk>>1, h = blk&1): row i, batches h*32..h*32+31.
// Zero intra-cell cross-WG comms; single producer->consumer flag per cell.
__global__ __launch_bounds__(512, 2) void k_grid(
    char* __restrict__ wsb, const float* __restrict__ bc, float* __restrict__ out)
{
    const _Float16* WtH = (const _Float16*)(wsb + OFF_WTH);
    const _Float16* WcH = (const _Float16*)(wsb + OFF_WCH);
    const float*  biasG = (const float*)(wsb + OFF_BIASG);
    const _Float16* xH  = (const _Float16*)(wsb + OFF_XH);
    float* hcF = (float*)(wsb + OFF_HCF);
    int* rowflag = (int*)(wsb + OFF_FLAGS);

    __shared__ __align__(16) _Float16 As[32][328];   // A staging; cols 0..255 reused as hnew
    __shared__ __align__(16) float blendRow[32][132]; // fp32 row-above state (pad 132: no col conflicts)
    __shared__ __align__(16) float hcPrev[32][132];   // fp32 own previous-col hc (persistent)

    const int blk = blockIdx.x;
    const int i = blk >> 1, h = blk & 1;
    const int tid = threadIdx.x;
    const int w = tid >> 6, l = tid & 63;
    const int l15 = l & 15, lhi = l >> 4;
    const int ko = lhi*8;
    const int ch0 = w*32 + l15, ch1 = ch0 + 16;      // wave's 2 channel groups
    const int b = tid >> 4, q = tid & 15;            // staging decomposition

    // ---- weight preload into registers (once) ----
    // bA/bB: [0..9]=g0 ks0-9, [10..19]=g1, [20..21]=g2 ks0-1, [22..29]=g3 ks2-9
    half8 bA[30], bB[30];
    #pragma unroll
    for (int ks = 0; ks < 10; ++ks) {
        bA[ks]    = *(const half8*)&WtH[(ull)(      ch0)*320 + ks*32 + ko];
        bA[10+ks] = *(const half8*)&WtH[(ull)(256 + ch0)*320 + ks*32 + ko];
        bB[ks]    = *(const half8*)&WtH[(ull)(      ch1)*320 + ks*32 + ko];
        bB[10+ks] = *(const half8*)&WtH[(ull)(256 + ch1)*320 + ks*32 + ko];
    }
    #pragma unroll
    for (int ks = 0; ks < 2; ++ks) {
        bA[20+ks] = *(const half8*)&WtH[(ull)(512 + ch0)*320 + ks*32 + ko];
        bB[20+ks] = *(const half8*)&WtH[(ull)(512 + ch1)*320 + ks*32 + ko];
    }
    #pragma unroll
    for (int ks = 2; ks < 10; ++ks) {
        bA[20+ks] = *(const half8*)&WtH[(ull)(768 + ch0)*320 + ks*32 + ko];
        bB[20+ks] = *(const half8*)&WtH[(ull)(768 + ch1)*320 + ks*32 + ko];
    }
    const float biA0 = biasG[ch0], biA1 = biasG[256+ch0], biA2 = biasG[512+ch0], biA3 = biasG[768+ch0];
    const float biB0 = biasG[ch1], biB1 = biasG[256+ch1], biB2 = biasG[512+ch1], biB3 = biasG[768+ch1];
    // compress: wave w -> out cols w*16..+15, M-tiles 0,1
    const int ccol = w*16 + l15;
    const float bcv = bc[ccol];
    half8 wcr[8];
    #pragma unroll
    for (int s = 0; s < 8; ++s)
        wcr[s] = *(const half8*)&WcH[(ull)ccol*256 + s*32 + ko];

    const int bg = h*32 + b;                         // global batch row for staging

    for (int j = 0; j < 32; ++j) {
        // x prefetch (independent of neighbors; hides under poll)
        uint2 xv = *(const uint2*)&xH[((ull)(i*32 + j)*64 + bg)*64 + q*4];
        // ---- wait for row above at col j ----
        if (tid == 0 && i > 0)
            while (ldrlx(&rowflag[blk - 2]) < j + 1) __builtin_amdgcn_s_sleep(1);
        __syncthreads();   // S1

        // ---- stage A + blend ----
        *(uint2*)&As[b][q*4] = xv;                    // k 0..63
        if (i > 0) {                                  // k 64..191 from row above (LLC)
            const float* s = hcF + ((ull)(((i-1)&1)*32 + j)*64 + bg)*128 + q*8;
            float2 f0 = up64(ald64(s));     float2 f1 = up64(ald64(s+2));
            float2 f2 = up64(ald64(s+4));   float2 f3 = up64(ald64(s+6));
            *(float2*)&blendRow[b][q*8]   = f0;  *(float2*)&blendRow[b][q*8+2] = f1;
            *(float2*)&blendRow[b][q*8+4] = f2;  *(float2*)&blendRow[b][q*8+6] = f3;
            half8 hh = {(_Float16)f0.x,(_Float16)f0.y,(_Float16)f1.x,(_Float16)f1.y,
                        (_Float16)f2.x,(_Float16)f2.y,(_Float16)f3.x,(_Float16)f3.y};
            *(half8*)&As[b][64 + q*8] = hh;
        } else {
            float2 z2 = make_float2(0.f, 0.f);
            *(float2*)&blendRow[b][q*8]   = z2;  *(float2*)&blendRow[b][q*8+2] = z2;
            *(float2*)&blendRow[b][q*8+4] = z2;  *(float2*)&blendRow[b][q*8+6] = z2;
            half8 hz = {};
            *(half8*)&As[b][64 + q*8] = hz;
        }
        if (j > 0) {                                  // k 192..319 from own prev col (LDS)
            half8 hh = {(_Float16)hcPrev[b][q*8+0],(_Float16)hcPrev[b][q*8+1],
                        (_Float16)hcPrev[b][q*8+2],(_Float16)hcPrev[b][q*8+3],
                        (_Float16)hcPrev[b][q*8+4],(_Float16)hcPrev[b][q*8+5],
                        (_Float16)hcPrev[b][q*8+6],(_Float16)hcPrev[b][q*8+7]};
            *(half8*)&As[b][192 + q*8] = hh;
        } else {
            float2 z2 = make_float2(0.f, 0.f);
            *(float2*)&hcPrev[b][q*8]   = z2;  *(float2*)&hcPrev[b][q*8+2] = z2;
            *(float2*)&hcPrev[b][q*8+4] = z2;  *(float2*)&hcPrev[b][q*8+6] = z2;
            half8 hz = {};
            *(half8*)&As[b][192 + q*8] = hz;
        }
        __syncthreads();   // S2

        // ---- gate GEMM: all-register B, LDS A; skip zero-padded K blocks ----
        f32x4 acc[2][4][2];
        #pragma unroll
        for (int m = 0; m < 2; ++m) {
            acc[0][0][m] = (f32x4){biA0,biA0,biA0,biA0};
            acc[0][1][m] = (f32x4){biA1,biA1,biA1,biA1};
            acc[0][2][m] = (f32x4){biA2,biA2,biA2,biA2};
            acc[0][3][m] = (f32x4){biA3,biA3,biA3,biA3};
            acc[1][0][m] = (f32x4){biB0,biB0,biB0,biB0};
            acc[1][1][m] = (f32x4){biB1,biB1,biB1,biB1};
            acc[1][2][m] = (f32x4){biB2,biB2,biB2,biB2};
            acc[1][3][m] = (f32x4){biB3,biB3,biB3,biB3};
        }
        #pragma unroll
        for (int ks = 0; ks < 10; ++ks) {
            half8 a0 = *(const half8*)&As[l15][ks*32 + ko];
            half8 a1 = *(const half8*)&As[16 + l15][ks*32 + ko];
            acc[0][0][0] = __builtin_amdgcn_mfma_f32_16x16x32_f16(a0, bA[ks],    acc[0][0][0], 0,0,0);
            acc[0][0][1] = __builtin_amdgcn_mfma_f32_16x16x32_f16(a1, bA[ks],    acc[0][0][1], 0,0,0);
            acc[0][1][0] = __builtin_amdgcn_mfma_f32_16x16x32_f16(a0, bA[10+ks], acc[0][1][0], 0,0,0);
            acc[0][1][1] = __builtin_amdgcn_mfma_f32_16x16x32_f16(a1, bA[10+ks], acc[0][1][1], 0,0,0);
            acc[1][0][0] = __builtin_amdgcn_mfma_f32_16x16x32_f16(a0, bB[ks],    acc[1][0][0], 0,0,0);
            acc[1][0][1] = __builtin_amdgcn_mfma_f32_16x16x32_f16(a1, bB[ks],    acc[1][0][1], 0,0,0);
            acc[1][1][0] = __builtin_amdgcn_mfma_f32_16x16x32_f16(a0, bB[10+ks], acc[1][1][0], 0,0,0);
            acc[1][1][1] = __builtin_amdgcn_mfma_f32_16x16x32_f16(a1, bB[10+ks], acc[1][1][1], 0,0,0);
            if (ks < 2) {
                acc[0][2][0] = __builtin_amdgcn_mfma_f32_16x16x32_f16(a0, bA[20+ks], acc[0][2][0], 0,0,0);
                acc[0][2][1] = __builtin_amdgcn_mfma_f32_16x16x32_f16(a1, bA[20+ks], acc[0][2][1], 0,0,0);
                acc[1][2][0] = __builtin_amdgcn_mfma_f32_16x16x32_f16(a0, bB[20+ks], acc[1][2][0], 0,0,0);
                acc[1][2][1] = __builtin_amdgcn_mfma_f32_16x16x32_f16(a1, bB[20+ks], acc[1][2][1], 0,0,0);
            } else {
                acc[0][3][0] = __builtin_amdgcn_mfma_f32_16x16x32_f16(a0, bA[20+ks], acc[0][3][0], 0,0,0);
                acc[0][3][1] = __builtin_amdgcn_mfma_f32_16x16x32_f16(a1, bA[20+ks], acc[0][3][1], 0,0,0);
                acc[1][3][0] = __builtin_amdgcn_mfma_f32_16x16x32_f16(a0, bB[20+ks], acc[1][3][0], 0,0,0);
                acc[1][3][1] = __builtin_amdgcn_mfma_f32_16x16x32_f16(a1, bB[20+ks], acc[1][3][1], 0,0,0);
            }
        }
        // ---- gate nonlinearities (in-lane; D row = m*16+lhi*4+r, col = ch) ----
        float hnv[2][2][4];
        #pragma unroll
        for (int cg = 0; cg < 2; ++cg) {
            const int c = w*32 + cg*16 + l15;
            #pragma unroll
            for (int m = 0; m < 2; ++m) {
                #pragma unroll
                for (int r = 0; r < 4; ++r) {
                    const int row = m*16 + lhi*4 + r;
                    float rg = 1.f/(1.f + __expf(-acc[cg][0][m][r]));
                    float zg = 1.f/(1.f + __expf(-acc[cg][1][m][r]));
                    float e2 = __expf(2.f*(acc[cg][2][m][r] + rg*acc[cg][3][m][r]));
                    float ng = 1.f - 2.f/(e2 + 1.f);
                    float hv = (c < 128) ? blendRow[row][c] : hcPrev[row][c - 128];
                    hnv[cg][m][r] = (1.f - zg)*ng + zg*hv;
                }
            }
        }
        __syncthreads();   // S3: all A/blend reads done
        #pragma unroll
        for (int cg = 0; cg < 2; ++cg) {
            const int c = w*32 + cg*16 + l15;
            #pragma unroll
            for (int m = 0; m < 2; ++m)
                #pragma unroll
                for (int r = 0; r < 4; ++r)
                    As[m*16 + lhi*4 + r][c] = (_Float16)hnv[cg][m][r];
        }
        __syncthreads();   // S4: hnew complete
        // ---- compress: h_c = hnew @ Wc.T + bc (register Wc) ----
        f32x4 c0 = (f32x4){bcv,bcv,bcv,bcv};
        f32x4 c1 = (f32x4){bcv,bcv,bcv,bcv};
        #pragma unroll
        for (int s = 0; s < 8; ++s) {
            half8 a0 = *(const half8*)&As[l15][s*32 + ko];
            half8 a1 = *(const half8*)&As[16 + l15][s*32 + ko];
            c0 = __builtin_amdgcn_mfma_f32_16x16x32_f16(a0, wcr[s], c0, 0,0,0);
            c1 = __builtin_amdgcn_mfma_f32_16x16x32_f16(a1, wcr[s], c1, 0,0,0);
        }
        #pragma unroll
        for (int r = 0; r < 4; ++r) {
            hcPrev[     lhi*4 + r][ccol] = c0[r];
            hcPrev[16 + lhi*4 + r][ccol] = c1[r];
        }
        __syncthreads();   // S5: hcPrev(i,j) complete in LDS
        // ---- export hc to LLC (consumed by row i+1) ----
        {
            float* dst = hcF + ((ull)((i&1)*32 + j)*64 + bg)*128 + q*8;
            #pragma unroll
            for (int e = 0; e < 4; ++e) {
                union { float f[2]; ull u; } pv;
                pv.f[0] = hcPrev[b][q*8 + e*2];
                pv.f[1] = hcPrev[b][q*8 + e*2 + 1];
                ast64(dst + e*2, pv.u);
            }
            if (i == 31 && j == 31) {
                float* od = out + bg*128 + q*8;
                #pragma unroll
                for (int e = 0; e < 8; ++e) od[e] = hcPrev[b][q*8 + e];
            }
        }
        __syncthreads();   // S6: all waves' stores drained (vmcnt(0) at barrier)
        if (tid == 0)
            __hip_atomic_store(&rowflag[blk], j + 1, __ATOMIC_RELEASE, __HIP_MEMORY_SCOPE_AGENT);
    }
}

extern "C" void kernel_launch(void* const* d_in, const int* in_sizes, int n_in,
                              void* d_out, int out_size, void* d_ws, size_t ws_size,
                              hipStream_t stream)
{
    const float* x    = (const float*)d_in[0];
    const float* We   = (const float*)d_in[1];
    const float* be   = (const float*)d_in[2];
    const float* W_ih = (const float*)d_in[3];
    const float* b_ih = (const float*)d_in[4];
    const float* W_hh = (const float*)d_in[5];
    const float* b_hh = (const float*)d_in[6];
    const float* Wc   = (const float*)d_in[7];
    const float* bc   = (const float*)d_in[8];
    char* wsb = (char*)d_ws;
    float* Wx     = (float*)(wsb + OFF_WX);
    _Float16* WtH = (_Float16*)(wsb + OFF_WTH);
    _Float16* WcH = (_Float16*)(wsb + OFF_WCH);
    float* biasG  = (float*)(wsb + OFF_BIASG);
    _Float16* xH  = (_Float16*)(wsb + OFF_XH);
    int* flags    = (int*)(wsb + OFF_FLAGS);
    float* out    = (float*)d_out;

    k_build_wx<<<192, 256, 0, stream>>>(W_ih, We, Wx);
    k_prep_wt<<<1024, 256, 0, stream>>>(Wx, W_hh, WtH);
    k_prep_bias<<<4, 256, 0, stream>>>(b_ih, b_hh, W_ih, be, biasG);
    k_prep_wc<<<32, 256, 0, stream>>>(Wc, WcH);
    k_prep_x<<<1024, 256, 0, stream>>>(x, xH);
    hipMemsetAsync(flags, 0, 64*sizeof(int), stream);
    k_grid<<<64, 512, 0, stream>>>(wsb, bc, out);
}

// Round 6
// 1132.880 us; speedup vs baseline: 1.1004x; 1.1004x over previous
//
#include <hip/hip_runtime.h>

typedef _Float16 half8 __attribute__((ext_vector_type(8)));
typedef float f32x4 __attribute__((ext_vector_type(4)));
typedef unsigned long long ull;

// ---- ws layout (byte offsets) ----
#define OFF_WTP   0u          // WtP  fp16 packed gate frags [16 wv-slots][30 frags][512] = 491520
#define OFF_WCP   491520u     // WcP  fp16 packed compress frags [8][8][512] = 65536
#define OFF_BIASG 557056u     // biasG f32 [1024] = 4096
#define OFF_WX    561152u     // Wx f32 [768][64] = 196608
#define OFF_XH    757760u     // xH fp16 [1024][64][64] = 8388608
#define OFF_HCH   9146368u    // hcH fp16 [2][32][64][128] = 1048576
#define OFF_HNX   10194944u   // hnX fp16 [32][2][64][256] = 2097152
#define OFF_FLAGS 12292096u   // 128 flags x 64-int padding = 32768
// total ~12.3 MB

// ---------------- coherent helpers ----------------
__device__ __forceinline__ int ldrlx(const int* p) {
    return __hip_atomic_load(p, __ATOMIC_RELAXED, __HIP_MEMORY_SCOPE_AGENT);
}
__device__ __forceinline__ ull ald64(const void* p) {
    return __hip_atomic_load((const ull*)p, __ATOMIC_RELAXED, __HIP_MEMORY_SCOPE_AGENT);
}
__device__ __forceinline__ void strel(int* p, int v) {
    __hip_atomic_store(p, v, __ATOMIC_RELEASE, __HIP_MEMORY_SCOPE_AGENT);
}

// ---------------- prep kernels ----------------
__global__ __launch_bounds__(256) void k_build_wx(
    const float* __restrict__ W_ih, const float* __restrict__ We,
    float* __restrict__ Wx)
{
    __shared__ float WeS[128][64];
    const int tid = threadIdx.x;
    #pragma unroll
    for (int q = 0; q < 8; ++q) {
        int p = q*256 + tid;
        int e = p >> 4, k4 = p & 15;
        *(float4*)&WeS[e][k4*4] = *(const float4*)&We[e*64 + k4*4];
    }
    __syncthreads();
    int idx = blockIdx.x*256 + tid;     // 49152 -> 192 blocks
    int r = idx >> 6, k = idx & 63;
    float acc = 0.f;
    #pragma unroll 4
    for (int e = 0; e < 128; ++e) acc = fmaf(W_ih[r*128 + e], WeS[e][k], acc);
    Wx[idx] = acc;
}

// gate weights packed per (side s, wave w, frag f): frag = 64 lanes x 8 halves.
// frag f: 0-9 g0 ks=f; 10-19 g1 ks=f-10; 20-21 g2 ks=f-20; 22-29 g3 ks=f-20.
__global__ __launch_bounds__(512) void k_prep_wtp(
    const float* __restrict__ Wx, const float* __restrict__ W_hh,
    _Float16* __restrict__ WtP)
{
    int bid = blockIdx.x;               // 480 = 16 slots * 30 frags
    int sw = bid / 30, f = bid % 30;
    int s = sw >> 3, w = sw & 7;
    int t = threadIdx.x;
    int l = t >> 3, e = t & 7;
    int g, ks;
    if (f < 10)      { g = 0; ks = f; }
    else if (f < 20) { g = 1; ks = f - 10; }
    else if (f < 22) { g = 2; ks = f - 20; }
    else             { g = 3; ks = f - 20; }
    int c = s*128 + w*16 + (l & 15);
    int k = ks*32 + (l >> 4)*8 + e;
    float v;
    if (k < 64) v = Wx[(g*256 + c)*64 + k];              // only g0,g1,g2 have ks<2
    else {
        int rr = (g == 3) ? (512 + c) : (g*256 + c);
        v = W_hh[rr*256 + (k - 64)];
    }
    WtP[(ull)bid*512 + t] = (_Float16)v;
}

// compress weights packed per (side s, wave w<4, frag f=0..7)
__global__ __launch_bounds__(512) void k_prep_wcp(
    const float* __restrict__ Wc, _Float16* __restrict__ WcP)
{
    int bid = blockIdx.x;               // 64 = 8 slots * 8 frags
    int sw = bid >> 3, f = bid & 7;
    int s = sw >> 2, w = sw & 3;
    int t = threadIdx.x;
    int l = t >> 3, e = t & 7;
    int oc = s*64 + w*16 + (l & 15);
    int k = f*32 + (l >> 4)*8 + e;
    WcP[(ull)bid*512 + t] = (_Float16)Wc[oc*256 + k];
}

__global__ __launch_bounds__(256) void k_prep_bias(
    const float* __restrict__ b_ih, const float* __restrict__ b_hh,
    const float* __restrict__ W_ih, const float* __restrict__ be,
    float* __restrict__ biasG)
{
    int row = blockIdx.x*256 + threadIdx.x;   // 1024
    int g = row >> 8, c = row & 255;
    float v;
    if (g < 3) {
        int r = g*256 + c;
        float bx = b_ih[r];
        #pragma unroll 4
        for (int e = 0; e < 128; ++e) bx = fmaf(W_ih[r*128 + e], be[e], bx);
        v = (g == 0) ? bx + b_hh[c] : (g == 1) ? bx + b_hh[256 + c] : bx;
    } else v = b_hh[512 + c];
    biasG[row] = v;
}

__global__ __launch_bounds__(256) void k_prep_x(
    const float* __restrict__ x, _Float16* __restrict__ xH)
{
    int cell = blockIdx.x;              // 1024
    int i = cell >> 5, j = cell & 31;
    int b = threadIdx.x >> 2, k16 = (threadIdx.x & 3)*16;
    const float* src = &x[((b*32 + i)*32 + j)*64 + k16];
    _Float16* dst = &xH[((ull)cell*64 + b)*64 + k16];
    #pragma unroll
    for (int kk = 0; kk < 16; kk += 4) {
        float4 v = *(const float4*)&src[kk];
        dst[kk+0] = (_Float16)v.x; dst[kk+1] = (_Float16)v.y;
        dst[kk+2] = (_Float16)v.z; dst[kk+3] = (_Float16)v.w;
    }
}

// ---------------- persistent 2D-GRU: channel-split, register-resident weights
// 64 WGs x 512 thr. WG (i = blk>>1, s = blk&1): row i, channels s*128..+127,
// full batch 64. Handoff: normal 16B stores + release flag (wbl2 -> MALL);
// consumers read via relaxed sc1 loads (no cache inv, weights stay in L2).
#define CF(idx) (flags + (idx)*64)
#define HF(idx) (flags + (64 + (idx))*64)

__global__ void __launch_bounds__(512)
__attribute__((amdgpu_waves_per_eu(2, 2)))
k_grid(char* __restrict__ wsb, const float* __restrict__ bcb, float* __restrict__ out)
{
    const _Float16* WtP = (const _Float16*)(wsb + OFF_WTP);
    const _Float16* WcP = (const _Float16*)(wsb + OFF_WCP);
    const float*  biasG = (const float*)(wsb + OFF_BIASG);
    const _Float16* xH  = (const _Float16*)(wsb + OFF_XH);
    _Float16* hcH = (_Float16*)(wsb + OFF_HCH);
    _Float16* hnX = (_Float16*)(wsb + OFF_HNX);
    int* flags = (int*)(wsb + OFF_FLAGS);

    __shared__ __align__(16) _Float16 As[64][328];  // [b][k]; cols 0..255 reused as hnew
    __shared__ __align__(16) _Float16 hcO[64][72];  // compress output staging (64 cols)

    const int blk = blockIdx.x;
    const int i = blk >> 1, s = blk & 1;
    const int tid = threadIdx.x;
    const int w = tid >> 6, l = tid & 63;
    const int l15 = l & 15, lhi = l >> 4;
    const int ko = lhi*8;
    const int c = s*128 + w*16 + l15;              // gate channel
    const int b8 = tid >> 3, q8 = tid & 7;         // staging decomposition

    // ---- gate weights -> registers (once; 30 frags = 120 VGPR/lane) ----
    half8 bA[30];
    #pragma unroll
    for (int f = 0; f < 30; ++f)
        bA[f] = *(const half8*)&WtP[((ull)((s*8 + w)*30 + f))*512 + l*8];
    const float bi0 = biasG[c],       bi1 = biasG[256 + c];
    const float bi2 = biasG[512 + c], bi3 = biasG[768 + c];
    // compress constants (waves 0-3)
    const int ol = w*16 + l15;                      // local out col
    const float bcv = (w < 4) ? bcb[s*64 + ol] : 0.f;

    for (int j = 0; j < 32; ++j) {
        // x prefetch (independent; hides under polls)
        uint4 xv = *(const uint4*)&xH[((ull)(i*32 + j)*64 + b8)*64 + q8*8];
        if (tid == 0) {
            if (i > 0) {
                while (ldrlx(CF((i-1)*2 + 0)) < j + 1) __builtin_amdgcn_s_sleep(1);
                while (ldrlx(CF((i-1)*2 + 1)) < j + 1) __builtin_amdgcn_s_sleep(1);
            }
            if (j > 0)
                while (ldrlx(CF(i*2 + (1 - s))) < j) __builtin_amdgcn_s_sleep(1);
        }
        __syncthreads();   // S1

        // ---- stage A: x | row-above hc | own-prev hc (MALL reads) ----
        *(uint4*)&As[b8][q8*8] = xv;
        if (i > 0) {
            const _Float16* src = hcH + ((ull)((((i-1)&1)*32 + j)*64 + b8))*128 + q8*16;
            ull u0 = ald64(src), u1 = ald64(src+4), u2 = ald64(src+8), u3 = ald64(src+12);
            *(ull*)&As[b8][64 + q8*16]      = u0;
            *(ull*)&As[b8][64 + q8*16 + 4]  = u1;
            *(ull*)&As[b8][64 + q8*16 + 8]  = u2;
            *(ull*)&As[b8][64 + q8*16 + 12] = u3;
        } else {
            *(ull*)&As[b8][64 + q8*16]      = 0ull;
            *(ull*)&As[b8][64 + q8*16 + 4]  = 0ull;
            *(ull*)&As[b8][64 + q8*16 + 8]  = 0ull;
            *(ull*)&As[b8][64 + q8*16 + 12] = 0ull;
        }
        if (j > 0) {
            const _Float16* src = hcH + ((ull)(((i&1)*32 + (j-1))*64 + b8))*128 + q8*16;
            ull u0 = ald64(src), u1 = ald64(src+4), u2 = ald64(src+8), u3 = ald64(src+12);
            *(ull*)&As[b8][192 + q8*16]      = u0;
            *(ull*)&As[b8][192 + q8*16 + 4]  = u1;
            *(ull*)&As[b8][192 + q8*16 + 8]  = u2;
            *(ull*)&As[b8][192 + q8*16 + 12] = u3;
        } else {
            *(ull*)&As[b8][192 + q8*16]      = 0ull;
            *(ull*)&As[b8][192 + q8*16 + 4]  = 0ull;
            *(ull*)&As[b8][192 + q8*16 + 8]  = 0ull;
            *(ull*)&As[b8][192 + q8*16 + 12] = 0ull;
        }
        __syncthreads();   // S2

        // ---- gate GEMM: M=64, 16 ch/wave, K=320 (sparse: 30 frags) ----
        f32x4 g0[4], g1[4], g2[4], g3[4];
        #pragma unroll
        for (int m = 0; m < 4; ++m) {
            g0[m] = (f32x4){bi0, bi0, bi0, bi0};
            g1[m] = (f32x4){bi1, bi1, bi1, bi1};
            g2[m] = (f32x4){bi2, bi2, bi2, bi2};
            g3[m] = (f32x4){bi3, bi3, bi3, bi3};
        }
        #pragma unroll
        for (int ks = 0; ks < 10; ++ks) {
            half8 a0 = *(const half8*)&As[     l15][ks*32 + ko];
            half8 a1 = *(const half8*)&As[16 + l15][ks*32 + ko];
            half8 a2 = *(const half8*)&As[32 + l15][ks*32 + ko];
            half8 a3 = *(const half8*)&As[48 + l15][ks*32 + ko];
            g0[0] = __builtin_amdgcn_mfma_f32_16x16x32_f16(a0, bA[ks], g0[0], 0,0,0);
            g0[1] = __builtin_amdgcn_mfma_f32_16x16x32_f16(a1, bA[ks], g0[1], 0,0,0);
            g0[2] = __builtin_amdgcn_mfma_f32_16x16x32_f16(a2, bA[ks], g0[2], 0,0,0);
            g0[3] = __builtin_amdgcn_mfma_f32_16x16x32_f16(a3, bA[ks], g0[3], 0,0,0);
            g1[0] = __builtin_amdgcn_mfma_f32_16x16x32_f16(a0, bA[10+ks], g1[0], 0,0,0);
            g1[1] = __builtin_amdgcn_mfma_f32_16x16x32_f16(a1, bA[10+ks], g1[1], 0,0,0);
            g1[2] = __builtin_amdgcn_mfma_f32_16x16x32_f16(a2, bA[10+ks], g1[2], 0,0,0);
            g1[3] = __builtin_amdgcn_mfma_f32_16x16x32_f16(a3, bA[10+ks], g1[3], 0,0,0);
            if (ks < 2) {
                g2[0] = __builtin_amdgcn_mfma_f32_16x16x32_f16(a0, bA[20+ks], g2[0], 0,0,0);
                g2[1] = __builtin_amdgcn_mfma_f32_16x16x32_f16(a1, bA[20+ks], g2[1], 0,0,0);
                g2[2] = __builtin_amdgcn_mfma_f32_16x16x32_f16(a2, bA[20+ks], g2[2], 0,0,0);
                g2[3] = __builtin_amdgcn_mfma_f32_16x16x32_f16(a3, bA[20+ks], g2[3], 0,0,0);
            } else {
                g3[0] = __builtin_amdgcn_mfma_f32_16x16x32_f16(a0, bA[20+ks], g3[0], 0,0,0);
                g3[1] = __builtin_amdgcn_mfma_f32_16x16x32_f16(a1, bA[20+ks], g3[1], 0,0,0);
                g3[2] = __builtin_amdgcn_mfma_f32_16x16x32_f16(a2, bA[20+ks], g3[2], 0,0,0);
                g3[3] = __builtin_amdgcn_mfma_f32_16x16x32_f16(a3, bA[20+ks], g3[3], 0,0,0);
            }
        }
        // ---- gate nonlinearities (blend h read from fp16 A regions) ----
        float hn[4][4];
        #pragma unroll
        for (int m = 0; m < 4; ++m) {
            #pragma unroll
            for (int r = 0; r < 4; ++r) {
                const int row = m*16 + lhi*4 + r;
                float rg = 1.f/(1.f + __expf(-g0[m][r]));
                float zg = 1.f/(1.f + __expf(-g1[m][r]));
                float e2 = __expf(2.f*(g2[m][r] + rg*g3[m][r]));
                float ng = 1.f - 2.f/(e2 + 1.f);
                float hv = (s == 0) ? (float)As[row][64 + c]
                                    : (float)As[row][192 + w*16 + l15];
                hn[m][r] = (1.f - zg)*ng + zg*hv;
            }
        }
        __syncthreads();   // S3: all A/blend reads done
        #pragma unroll
        for (int m = 0; m < 4; ++m)
            #pragma unroll
            for (int r = 0; r < 4; ++r)
                As[m*16 + lhi*4 + r][c] = (_Float16)hn[m][r];
        __syncthreads();   // S4: hnew (own half) in LDS
        // compress weights (waves 0-3, short live range)
        half8 wcr[8];
        if (w < 4) {
            #pragma unroll
            for (int f = 0; f < 8; ++f)
                wcr[f] = *(const half8*)&WcP[((ull)((s*4 + w)*8 + f))*512 + l*8];
        }
        // ---- export own hnew half (normal stores; wbl2 via release flag) ----
        {
            _Float16* dst = hnX + ((ull)((i*2 + (j&1))*64 + b8))*256 + s*128 + q8*16;
            *(uint4*)dst       = *(const uint4*)&As[b8][s*128 + q8*16];
            *(uint4*)(dst + 8) = *(const uint4*)&As[b8][s*128 + q8*16 + 8];
        }
        __syncthreads();   // S5: all waves' stores issued+retired (vmcnt0)
        if (tid == 0) strel(HF(i*2 + s), j + 1);          // wbl2 + flag
        // ---- own-half compress overlapped with partner wait ----
        f32x4 cc[4];
        #pragma unroll
        for (int m = 0; m < 4; ++m) cc[m] = (f32x4){bcv, bcv, bcv, bcv};
        if (w < 4) {
            if (s == 0) {
                #pragma unroll
                for (int f = 0; f < 4; ++f) {
                    #pragma unroll
                    for (int m = 0; m < 4; ++m) {
                        half8 a = *(const half8*)&As[m*16 + l15][f*32 + ko];
                        cc[m] = __builtin_amdgcn_mfma_f32_16x16x32_f16(a, wcr[f], cc[m], 0,0,0);
                    }
                }
            } else {
                #pragma unroll
                for (int f = 4; f < 8; ++f) {
                    #pragma unroll
                    for (int m = 0; m < 4; ++m) {
                        half8 a = *(const half8*)&As[m*16 + l15][f*32 + ko];
                        cc[m] = __builtin_amdgcn_mfma_f32_16x16x32_f16(a, wcr[f], cc[m], 0,0,0);
                    }
                }
            }
        }
        if (tid == 256)    // wave 4 (idle in compress) polls partner hnew flag
            while (ldrlx(HF(i*2 + (1 - s))) < j + 1) __builtin_amdgcn_s_sleep(1);
        __syncthreads();   // S6
        // ---- read partner hnew half -> As ----
        {
            const _Float16* src = hnX + ((ull)((i*2 + (j&1))*64 + b8))*256 + (1-s)*128 + q8*16;
            ull u0 = ald64(src), u1 = ald64(src+4), u2 = ald64(src+8), u3 = ald64(src+12);
            *(ull*)&As[b8][(1-s)*128 + q8*16]      = u0;
            *(ull*)&As[b8][(1-s)*128 + q8*16 + 4]  = u1;
            *(ull*)&As[b8][(1-s)*128 + q8*16 + 8]  = u2;
            *(ull*)&As[b8][(1-s)*128 + q8*16 + 12] = u3;
        }
        __syncthreads();   // S7
        // ---- partner-half compress + stage output ----
        if (w < 4) {
            if (s == 0) {
                #pragma unroll
                for (int f = 4; f < 8; ++f) {
                    #pragma unroll
                    for (int m = 0; m < 4; ++m) {
                        half8 a = *(const half8*)&As[m*16 + l15][f*32 + ko];
                        cc[m] = __builtin_amdgcn_mfma_f32_16x16x32_f16(a, wcr[f], cc[m], 0,0,0);
                    }
                }
            } else {
                #pragma unroll
                for (int f = 0; f < 4; ++f) {
                    #pragma unroll
                    for (int m = 0; m < 4; ++m) {
                        half8 a = *(const half8*)&As[m*16 + l15][f*32 + ko];
                        cc[m] = __builtin_amdgcn_mfma_f32_16x16x32_f16(a, wcr[f], cc[m], 0,0,0);
                    }
                }
            }
            #pragma unroll
            for (int m = 0; m < 4; ++m)
                #pragma unroll
                for (int r = 0; r < 4; ++r)
                    hcO[m*16 + lhi*4 + r][ol] = (_Float16)cc[m][r];
        }
        __syncthreads();   // S8
        // ---- export hc slice (normal 16B stores) + final out ----
        {
            uint4 v = *(const uint4*)&hcO[b8][q8*8];
            *(uint4*)&hcH[((ull)(((i&1)*32 + j)*64 + b8))*128 + s*64 + q8*8] = v;
            if (i == 31 && j == 31) {
                float* od = out + b8*128 + s*64 + q8*8;
                #pragma unroll
                for (int e = 0; e < 8; ++e) od[e] = (float)hcO[b8][q8*8 + e];
            }
        }
        __syncthreads();   // S9: stores retired
        if (tid == 0) strel(CF(i*2 + s), j + 1);          // wbl2 + flag
    }
}

extern "C" void kernel_launch(void* const* d_in, const int* in_sizes, int n_in,
                              void* d_out, int out_size, void* d_ws, size_t ws_size,
                              hipStream_t stream)
{
    const float* x    = (const float*)d_in[0];
    const float* We   = (const float*)d_in[1];
    const float* be   = (const float*)d_in[2];
    const float* W_ih = (const float*)d_in[3];
    const float* b_ih = (const float*)d_in[4];
    const float* W_hh = (const float*)d_in[5];
    const float* b_hh = (const float*)d_in[6];
    const float* Wc   = (const float*)d_in[7];
    const float* bc   = (const float*)d_in[8];
    char* wsb = (char*)d_ws;
    float* Wx     = (float*)(wsb + OFF_WX);
    _Float16* WtP = (_Float16*)(wsb + OFF_WTP);
    _Float16* WcP = (_Float16*)(wsb + OFF_WCP);
    float* biasG  = (float*)(wsb + OFF_BIASG);
    _Float16* xH  = (_Float16*)(wsb + OFF_XH);
    int* flags    = (int*)(wsb + OFF_FLAGS);
    float* out    = (float*)d_out;

    k_build_wx<<<192, 256, 0, stream>>>(W_ih, We, Wx);
    k_prep_wtp<<<480, 512, 0, stream>>>(Wx, W_hh, WtP);
    k_prep_wcp<<<64, 512, 0, stream>>>(Wc, WcP);
    k_prep_bias<<<4, 256, 0, stream>>>(b_ih, b_hh, W_ih, be, biasG);
    k_prep_x<<<1024, 256, 0, stream>>>(x, xH);
    hipMemsetAsync(flags, 0, 128*64*sizeof(int), stream);
    k_grid<<<64, 512, 0, stream>>>(wsb, bc, out);
}

// Round 7
// 668.422 us; speedup vs baseline: 1.8650x; 1.6949x over previous
//
#include <hip/hip_runtime.h>

typedef _Float16 half8 __attribute__((ext_vector_type(8)));
typedef float f32x4 __attribute__((ext_vector_type(4)));
typedef unsigned long long ull;

// ---- ws layout (byte offsets) ----
#define OFF_WTP   0u          // WtP  fp16 packed gate frags [16 wv-slots][30 frags][512] = 491520
#define OFF_WCP   491520u     // WcP  fp16 packed compress frags [8][8][512] = 65536
#define OFF_BIASG 557056u     // biasG f32 [1024] = 4096
#define OFF_WX    561152u     // Wx f32 [768][64] = 196608
#define OFF_XH    757760u     // xH fp16 [1024][64][64] = 8388608
#define OFF_HCH   9146368u    // hcH fp16 [2][32][64][128] = 1048576
#define OFF_HNX   10194944u   // hnX fp16 [32][2][64][256] = 2097152
#define OFF_FLAGS 12292096u   // 128 flags x 64-int padding = 32768
// total ~12.3 MB

// ---- coherent helpers: ALL relaxed agent-scope (sc1 -> MALL), never acq/rel
__device__ __forceinline__ int ldrlx(const int* p) {
    return __hip_atomic_load(p, __ATOMIC_RELAXED, __HIP_MEMORY_SCOPE_AGENT);
}
__device__ __forceinline__ void astrlx(int* p, int v) {
    __hip_atomic_store(p, v, __ATOMIC_RELAXED, __HIP_MEMORY_SCOPE_AGENT);
}
__device__ __forceinline__ ull ald64(const void* p) {
    return __hip_atomic_load((const ull*)p, __ATOMIC_RELAXED, __HIP_MEMORY_SCOPE_AGENT);
}
__device__ __forceinline__ void ast64(void* p, ull v) {
    __hip_atomic_store((ull*)p, v, __ATOMIC_RELAXED, __HIP_MEMORY_SCOPE_AGENT);
}

// ---------------- prep kernels ----------------
__global__ __launch_bounds__(256) void k_build_wx(
    const float* __restrict__ W_ih, const float* __restrict__ We,
    float* __restrict__ Wx)
{
    __shared__ float WeS[128][64];
    const int tid = threadIdx.x;
    #pragma unroll
    for (int q = 0; q < 8; ++q) {
        int p = q*256 + tid;
        int e = p >> 4, k4 = p & 15;
        *(float4*)&WeS[e][k4*4] = *(const float4*)&We[e*64 + k4*4];
    }
    __syncthreads();
    int idx = blockIdx.x*256 + tid;     // 49152 -> 192 blocks
    int r = idx >> 6, k = idx & 63;
    float acc = 0.f;
    #pragma unroll 4
    for (int e = 0; e < 128; ++e) acc = fmaf(W_ih[r*128 + e], WeS[e][k], acc);
    Wx[idx] = acc;
}

// gate weights packed per (side s, wave w, frag f): frag = 64 lanes x 8 halves.
// frag f: 0-9 g0 ks=f; 10-19 g1 ks=f-10; 20-21 g2 ks=f-20; 22-29 g3 ks=f-20.
__global__ __launch_bounds__(512) void k_prep_wtp(
    const float* __restrict__ Wx, const float* __restrict__ W_hh,
    _Float16* __restrict__ WtP)
{
    int bid = blockIdx.x;               // 480 = 16 slots * 30 frags
    int sw = bid / 30, f = bid % 30;
    int s = sw >> 3, w = sw & 7;
    int t = threadIdx.x;
    int l = t >> 3, e = t & 7;
    int g, ks;
    if (f < 10)      { g = 0; ks = f; }
    else if (f < 20) { g = 1; ks = f - 10; }
    else if (f < 22) { g = 2; ks = f - 20; }
    else             { g = 3; ks = f - 20; }
    int c = s*128 + w*16 + (l & 15);
    int k = ks*32 + (l >> 4)*8 + e;
    float v;
    if (k < 64) v = Wx[(g*256 + c)*64 + k];              // only g0,g1,g2 have ks<2
    else {
        int rr = (g == 3) ? (512 + c) : (g*256 + c);
        v = W_hh[rr*256 + (k - 64)];
    }
    WtP[(ull)bid*512 + t] = (_Float16)v;
}

// compress weights packed per (side s, wave w<4, frag f=0..7)
__global__ __launch_bounds__(512) void k_prep_wcp(
    const float* __restrict__ Wc, _Float16* __restrict__ WcP)
{
    int bid = blockIdx.x;               // 64 = 8 slots * 8 frags
    int sw = bid >> 3, f = bid & 7;
    int s = sw >> 2, w = sw & 3;
    int t = threadIdx.x;
    int l = t >> 3, e = t & 7;
    int oc = s*64 + w*16 + (l & 15);
    int k = f*32 + (l >> 4)*8 + e;
    WcP[(ull)bid*512 + t] = (_Float16)Wc[oc*256 + k];
}

__global__ __launch_bounds__(256) void k_prep_bias(
    const float* __restrict__ b_ih, const float* __restrict__ b_hh,
    const float* __restrict__ W_ih, const float* __restrict__ be,
    float* __restrict__ biasG)
{
    int row = blockIdx.x*256 + threadIdx.x;   // 1024
    int g = row >> 8, c = row & 255;
    float v;
    if (g < 3) {
        int r = g*256 + c;
        float bx = b_ih[r];
        #pragma unroll 4
        for (int e = 0; e < 128; ++e) bx = fmaf(W_ih[r*128 + e], be[e], bx);
        v = (g == 0) ? bx + b_hh[c] : (g == 1) ? bx + b_hh[256 + c] : bx;
    } else v = b_hh[512 + c];
    biasG[row] = v;
}

__global__ __launch_bounds__(256) void k_prep_x(
    const float* __restrict__ x, _Float16* __restrict__ xH)
{
    int cell = blockIdx.x;              // 1024
    int i = cell >> 5, j = cell & 31;
    int b = threadIdx.x >> 2, k16 = (threadIdx.x & 3)*16;
    const float* src = &x[((b*32 + i)*32 + j)*64 + k16];
    _Float16* dst = &xH[((ull)cell*64 + b)*64 + k16];
    #pragma unroll
    for (int kk = 0; kk < 16; kk += 4) {
        float4 v = *(const float4*)&src[kk];
        dst[kk+0] = (_Float16)v.x; dst[kk+1] = (_Float16)v.y;
        dst[kk+2] = (_Float16)v.z; dst[kk+3] = (_Float16)v.w;
    }
}

// ---------------- persistent 2D-GRU: ch-split, NO cache-maintenance sync ----
// 64 WGs x 512 thr. WG (i = blk>>1, s = blk&1): row i, channels s*128..+127.
// All cross-WG data: relaxed sc1 (MALL). Flags: relaxed store after barrier
// (barrier's vmcnt(0) orders data-before-flag). Zero wbl2/inv in hot loop.
#define CF(idx) (flags + (idx)*64)
#define HF(idx) (flags + (64 + (idx))*64)

__global__ void __launch_bounds__(512, 2)
k_grid(char* __restrict__ wsb, const float* __restrict__ bcb, float* __restrict__ out)
{
    const _Float16* WtP = (const _Float16*)(wsb + OFF_WTP);
    const _Float16* WcP = (const _Float16*)(wsb + OFF_WCP);
    const float*  biasG = (const float*)(wsb + OFF_BIASG);
    const _Float16* xH  = (const _Float16*)(wsb + OFF_XH);
    _Float16* hcH = (_Float16*)(wsb + OFF_HCH);
    _Float16* hnX = (_Float16*)(wsb + OFF_HNX);
    int* flags = (int*)(wsb + OFF_FLAGS);

    __shared__ __align__(16) _Float16 As[64][328];  // [b][k]; cols 0..255 reused as hnew
    __shared__ __align__(16) _Float16 hcO[64][72];  // compress output staging (64 cols)

    const int blk = blockIdx.x;
    const int i = blk >> 1, s = blk & 1;
    const int tid = threadIdx.x;
    const int w = tid >> 6, l = tid & 63;
    const int l15 = l & 15, lhi = l >> 4;
    const int ko = lhi*8;
    const int c = s*128 + w*16 + l15;              // gate channel
    const int b8 = tid >> 3, q8 = tid & 7;         // staging decomposition

    // ---- gate weights -> registers (once; 30 frags = 120 VGPR/lane) ----
    half8 bA[30];
    #pragma unroll
    for (int f = 0; f < 30; ++f)
        bA[f] = *(const half8*)&WtP[((ull)((s*8 + w)*30 + f))*512 + l*8];
    const float bi0 = biasG[c],       bi1 = biasG[256 + c];
    const float bi2 = biasG[512 + c], bi3 = biasG[768 + c];
    // compress weights -> registers (waves 0-3)
    const int ol = w*16 + l15;                      // local out col
    const float bcv = (w < 4) ? bcb[s*64 + ol] : 0.f;
    half8 wcr[8];
    if (w < 4) {
        #pragma unroll
        for (int f = 0; f < 8; ++f)
            wcr[f] = *(const half8*)&WcP[((ull)((s*4 + w)*8 + f))*512 + l*8];
    }

    for (int j = 0; j < 32; ++j) {
        // x prefetch (independent; hides under polls)
        uint4 xv = *(const uint4*)&xH[((ull)(i*32 + j)*64 + b8)*64 + q8*8];
        if (tid == 0) {
            if (i > 0) {
                while (ldrlx(CF((i-1)*2 + 0)) < j + 1) __builtin_amdgcn_s_sleep(1);
                while (ldrlx(CF((i-1)*2 + 1)) < j + 1) __builtin_amdgcn_s_sleep(1);
            }
            if (j > 0)
                while (ldrlx(CF(i*2 + (1 - s))) < j) __builtin_amdgcn_s_sleep(1);
        }
        __syncthreads();   // S1

        // ---- stage A: x | row-above hc | own-prev hc (MALL reads) ----
        *(uint4*)&As[b8][q8*8] = xv;
        if (i > 0) {
            const _Float16* src = hcH + ((ull)((((i-1)&1)*32 + j)*64 + b8))*128 + q8*16;
            ull u0 = ald64(src), u1 = ald64(src+4), u2 = ald64(src+8), u3 = ald64(src+12);
            *(ull*)&As[b8][64 + q8*16]      = u0;
            *(ull*)&As[b8][64 + q8*16 + 4]  = u1;
            *(ull*)&As[b8][64 + q8*16 + 8]  = u2;
            *(ull*)&As[b8][64 + q8*16 + 12] = u3;
        } else {
            *(ull*)&As[b8][64 + q8*16]      = 0ull;
            *(ull*)&As[b8][64 + q8*16 + 4]  = 0ull;
            *(ull*)&As[b8][64 + q8*16 + 8]  = 0ull;
            *(ull*)&As[b8][64 + q8*16 + 12] = 0ull;
        }
        if (j > 0) {
            const _Float16* src = hcH + ((ull)(((i&1)*32 + (j-1))*64 + b8))*128 + q8*16;
            ull u0 = ald64(src), u1 = ald64(src+4), u2 = ald64(src+8), u3 = ald64(src+12);
            *(ull*)&As[b8][192 + q8*16]      = u0;
            *(ull*)&As[b8][192 + q8*16 + 4]  = u1;
            *(ull*)&As[b8][192 + q8*16 + 8]  = u2;
            *(ull*)&As[b8][192 + q8*16 + 12] = u3;
        } else {
            *(ull*)&As[b8][192 + q8*16]      = 0ull;
            *(ull*)&As[b8][192 + q8*16 + 4]  = 0ull;
            *(ull*)&As[b8][192 + q8*16 + 8]  = 0ull;
            *(ull*)&As[b8][192 + q8*16 + 12] = 0ull;
        }
        __syncthreads();   // S2

        // ---- gate GEMM in 2 m-passes (acc 32 VGPR instead of 64) ----
        #pragma unroll
        for (int mp = 0; mp < 2; ++mp) {
            f32x4 g0[2], g1[2], g2[2], g3[2];
            #pragma unroll
            for (int m = 0; m < 2; ++m) {
                g0[m] = (f32x4){bi0, bi0, bi0, bi0};
                g1[m] = (f32x4){bi1, bi1, bi1, bi1};
                g2[m] = (f32x4){bi2, bi2, bi2, bi2};
                g3[m] = (f32x4){bi3, bi3, bi3, bi3};
            }
            #pragma unroll
            for (int ks = 0; ks < 10; ++ks) {
                half8 a0 = *(const half8*)&As[mp*32 +      l15][ks*32 + ko];
                half8 a1 = *(const half8*)&As[mp*32 + 16 + l15][ks*32 + ko];
                g0[0] = __builtin_amdgcn_mfma_f32_16x16x32_f16(a0, bA[ks],    g0[0], 0,0,0);
                g0[1] = __builtin_amdgcn_mfma_f32_16x16x32_f16(a1, bA[ks],    g0[1], 0,0,0);
                g1[0] = __builtin_amdgcn_mfma_f32_16x16x32_f16(a0, bA[10+ks], g1[0], 0,0,0);
                g1[1] = __builtin_amdgcn_mfma_f32_16x16x32_f16(a1, bA[10+ks], g1[1], 0,0,0);
                if (ks < 2) {
                    g2[0] = __builtin_amdgcn_mfma_f32_16x16x32_f16(a0, bA[20+ks], g2[0], 0,0,0);
                    g2[1] = __builtin_amdgcn_mfma_f32_16x16x32_f16(a1, bA[20+ks], g2[1], 0,0,0);
                } else {
                    g3[0] = __builtin_amdgcn_mfma_f32_16x16x32_f16(a0, bA[20+ks], g3[0], 0,0,0);
                    g3[1] = __builtin_amdgcn_mfma_f32_16x16x32_f16(a1, bA[20+ks], g3[1], 0,0,0);
                }
            }
            // nonlinearities for this m-pass (blend h from staged A regions)
            float hn[2][4];
            #pragma unroll
            for (int m = 0; m < 2; ++m) {
                #pragma unroll
                for (int r = 0; r < 4; ++r) {
                    const int row = mp*32 + m*16 + lhi*4 + r;
                    float rg = 1.f/(1.f + __expf(-g0[m][r]));
                    float zg = 1.f/(1.f + __expf(-g1[m][r]));
                    float e2 = __expf(2.f*(g2[m][r] + rg*g3[m][r]));
                    float ng = 1.f - 2.f/(e2 + 1.f);
                    float hv = (s == 0) ? (float)As[row][64 + c]
                                        : (float)As[row][192 + w*16 + l15];
                    hn[m][r] = (1.f - zg)*ng + zg*hv;
                }
            }
            __syncthreads();   // S3a/S3b: this pass's blend reads done
            #pragma unroll
            for (int m = 0; m < 2; ++m)
                #pragma unroll
                for (int r = 0; r < 4; ++r)
                    As[mp*32 + m*16 + lhi*4 + r][c] = (_Float16)hn[m][r];
        }
        __syncthreads();   // S4: hnew (own half) complete in LDS
        // ---- export own hnew half (relaxed sc1 stores -> MALL) ----
        {
            _Float16* dst = hnX + ((ull)((i*2 + (j&1))*64 + b8))*256 + s*128 + q8*16;
            ast64(dst,      *(const ull*)&As[b8][s*128 + q8*16]);
            ast64(dst + 4,  *(const ull*)&As[b8][s*128 + q8*16 + 4]);
            ast64(dst + 8,  *(const ull*)&As[b8][s*128 + q8*16 + 8]);
            ast64(dst + 12, *(const ull*)&As[b8][s*128 + q8*16 + 12]);
        }
        __syncthreads();   // S5: all waves' sc1 stores drained (vmcnt0)
        if (tid == 0) astrlx(HF(i*2 + s), j + 1);
        // ---- own-half compress overlapped with partner wait ----
        f32x4 cc[4];
        #pragma unroll
        for (int m = 0; m < 4; ++m) cc[m] = (f32x4){bcv, bcv, bcv, bcv};
        if (w < 4) {
            if (s == 0) {
                #pragma unroll
                for (int f = 0; f < 4; ++f)
                    #pragma unroll
                    for (int m = 0; m < 4; ++m) {
                        half8 a = *(const half8*)&As[m*16 + l15][f*32 + ko];
                        cc[m] = __builtin_amdgcn_mfma_f32_16x16x32_f16(a, wcr[f], cc[m], 0,0,0);
                    }
            } else {
                #pragma unroll
                for (int f = 4; f < 8; ++f)
                    #pragma unroll
                    for (int m = 0; m < 4; ++m) {
                        half8 a = *(const half8*)&As[m*16 + l15][f*32 + ko];
                        cc[m] = __builtin_amdgcn_mfma_f32_16x16x32_f16(a, wcr[f], cc[m], 0,0,0);
                    }
            }
        }
        if (tid == 256)    // wave 4 (idle in compress) polls partner hnew flag
            while (ldrlx(HF(i*2 + (1 - s))) < j + 1) __builtin_amdgcn_s_sleep(1);
        __syncthreads();   // S6
        // ---- read partner hnew half -> As (MALL) ----
        {
            const _Float16* src = hnX + ((ull)((i*2 + (j&1))*64 + b8))*256 + (1-s)*128 + q8*16;
            ull u0 = ald64(src), u1 = ald64(src+4), u2 = ald64(src+8), u3 = ald64(src+12);
            *(ull*)&As[b8][(1-s)*128 + q8*16]      = u0;
            *(ull*)&As[b8][(1-s)*128 + q8*16 + 4]  = u1;
            *(ull*)&As[b8][(1-s)*128 + q8*16 + 8]  = u2;
            *(ull*)&As[b8][(1-s)*128 + q8*16 + 12] = u3;
        }
        __syncthreads();   // S7
        // ---- partner-half compress + stage output ----
        if (w < 4) {
            if (s == 0) {
                #pragma unroll
                for (int f = 4; f < 8; ++f)
                    #pragma unroll
                    for (int m = 0; m < 4; ++m) {
                        half8 a = *(const half8*)&As[m*16 + l15][f*32 + ko];
                        cc[m] = __builtin_amdgcn_mfma_f32_16x16x32_f16(a, wcr[f], cc[m], 0,0,0);
                    }
            } else {
                #pragma unroll
                for (int f = 0; f < 4; ++f)
                    #pragma unroll
                    for (int m = 0; m < 4; ++m) {
                        half8 a = *(const half8*)&As[m*16 + l15][f*32 + ko];
                        cc[m] = __builtin_amdgcn_mfma_f32_16x16x32_f16(a, wcr[f], cc[m], 0,0,0);
                    }
            }
            #pragma unroll
            for (int m = 0; m < 4; ++m)
                #pragma unroll
                for (int r = 0; r < 4; ++r)
                    hcO[m*16 + lhi*4 + r][ol] = (_Float16)cc[m][r];
        }
        __syncthreads();   // S8
        // ---- export hc slice (relaxed sc1) + final out ----
        {
            ast64(&hcH[((ull)(((i&1)*32 + j)*64 + b8))*128 + s*64 + q8*8],
                  *(const ull*)&hcO[b8][q8*8]);
            ast64(&hcH[((ull)(((i&1)*32 + j)*64 + b8))*128 + s*64 + q8*8 + 4],
                  *(const ull*)&hcO[b8][q8*8 + 4]);
            if (i == 31 && j == 31) {
                float* od = out + b8*128 + s*64 + q8*8;
                #pragma unroll
                for (int e = 0; e < 8; ++e) od[e] = (float)hcO[b8][q8*8 + e];
            }
        }
        __syncthreads();   // S9: stores drained
        if (tid == 0) astrlx(CF(i*2 + s), j + 1);
    }
}

extern "C" void kernel_launch(void* const* d_in, const int* in_sizes, int n_in,
                              void* d_out, int out_size, void* d_ws, size_t ws_size,
                              hipStream_t stream)
{
    const float* x    = (const float*)d_in[0];
    const float* We   = (const float*)d_in[1];
    const float* be   = (const float*)d_in[2];
    const float* W_ih = (const float*)d_in[3];
    const float* b_ih = (const float*)d_in[4];
    const float* W_hh = (const float*)d_in[5];
    const float* b_hh = (const float*)d_in[6];
    const float* Wc   = (const float*)d_in[7];
    const float* bc   = (const float*)d_in[8];
    char* wsb = (char*)d_ws;
    float* Wx     = (float*)(wsb + OFF_WX);
    _Float16* WtP = (_Float16*)(wsb + OFF_WTP);
    _Float16* WcP = (_Float16*)(wsb + OFF_WCP);
    float* biasG  = (float*)(wsb + OFF_BIASG);
    _Float16* xH  = (_Float16*)(wsb + OFF_XH);
    int* flags    = (int*)(wsb + OFF_FLAGS);
    float* out    = (float*)d_out;

    k_build_wx<<<192, 256, 0, stream>>>(W_ih, We, Wx);
    k_prep_wtp<<<480, 512, 0, stream>>>(Wx, W_hh, WtP);
    k_prep_wcp<<<64, 512, 0, stream>>>(Wc, WcP);
    k_prep_bias<<<4, 256, 0, stream>>>(b_ih, b_hh, W_ih, be, biasG);
    k_prep_x<<<1024, 256, 0, stream>>>(x, xH);
    hipMemsetAsync(flags, 0, 128*64*sizeof(int), stream);
    k_grid<<<64, 512, 0, stream>>>(wsb, bc, out);
}

// Round 8
// 656.935 us; speedup vs baseline: 1.8977x; 1.0175x over previous
//
#include <hip/hip_runtime.h>

typedef _Float16 half8 __attribute__((ext_vector_type(8)));
typedef float f32x4 __attribute__((ext_vector_type(4)));
typedef unsigned long long ull;

// ---- ws layout (byte offsets) ----
#define OFF_WTP   0u          // WtP fp16 gate frags [16 slots][30 frags][512] = 491520
#define OFF_WCP   491520u     // WcP fp16 compress frags [8 w][8 f][512] = 65536
#define OFF_BIASG 557056u     // biasG f32 [1024] = 4096
#define OFF_WX    561152u     // Wx f32 [768][64] = 196608
#define OFF_XH    757760u     // xH fp16 [1024][64][64] = 8388608
#define OFF_HCP   9146368u    // hcP fp16 [2 s][2 ip][32 j][64 b][128] = 2097152
#define OFF_FLAGS 11243520u   // CF[64] x 64-int pad = 16384
// total ~11.26 MB

// ---- coherent helpers: relaxed agent-scope only (sc1 -> MALL), no acq/rel --
__device__ __forceinline__ int ldrlx(const int* p) {
    return __hip_atomic_load(p, __ATOMIC_RELAXED, __HIP_MEMORY_SCOPE_AGENT);
}
__device__ __forceinline__ void astrlx(int* p, int v) {
    __hip_atomic_store(p, v, __ATOMIC_RELAXED, __HIP_MEMORY_SCOPE_AGENT);
}
__device__ __forceinline__ ull ald64(const void* p) {
    return __hip_atomic_load((const ull*)p, __ATOMIC_RELAXED, __HIP_MEMORY_SCOPE_AGENT);
}
__device__ __forceinline__ void ast64(void* p, ull v) {
    __hip_atomic_store((ull*)p, v, __ATOMIC_RELAXED, __HIP_MEMORY_SCOPE_AGENT);
}

// ---------------- prep kernels ----------------
__global__ __launch_bounds__(256) void k_build_wx(
    const float* __restrict__ W_ih, const float* __restrict__ We,
    float* __restrict__ Wx)
{
    __shared__ float WeS[128][64];
    const int tid = threadIdx.x;
    #pragma unroll
    for (int q = 0; q < 8; ++q) {
        int p = q*256 + tid;
        int e = p >> 4, k4 = p & 15;
        *(float4*)&WeS[e][k4*4] = *(const float4*)&We[e*64 + k4*4];
    }
    __syncthreads();
    int idx = blockIdx.x*256 + tid;     // 49152 -> 192 blocks
    int r = idx >> 6, k = idx & 63;
    float acc = 0.f;
    #pragma unroll 4
    for (int e = 0; e < 128; ++e) acc = fmaf(W_ih[r*128 + e], WeS[e][k], acc);
    Wx[idx] = acc;
}

// gate weights packed per (side s, wave w, frag f): frag = 64 lanes x 8 halves.
// f: 0-9 g0 ks=f; 10-19 g1 ks=f-10; 20-21 g2 ks=f-20; 22-29 g3 ks=f-20.
__global__ __launch_bounds__(512) void k_prep_wtp(
    const float* __restrict__ Wx, const float* __restrict__ W_hh,
    _Float16* __restrict__ WtP)
{
    int bid = blockIdx.x;               // 480 = 16 slots * 30 frags
    int sw = bid / 30, f = bid % 30;
    int s = sw >> 3, w = sw & 7;
    int t = threadIdx.x;
    int l = t >> 3, e = t & 7;
    int g, ks;
    if (f < 10)      { g = 0; ks = f; }
    else if (f < 20) { g = 1; ks = f - 10; }
    else if (f < 22) { g = 2; ks = f - 20; }
    else             { g = 3; ks = f - 20; }
    int c = s*128 + w*16 + (l & 15);
    int k = ks*32 + (l >> 4)*8 + e;
    float v;
    if (k < 64) v = Wx[(g*256 + c)*64 + k];
    else {
        int rr = (g == 3) ? (512 + c) : (g*256 + c);
        v = W_hh[rr*256 + (k - 64)];
    }
    WtP[(ull)bid*512 + t] = (_Float16)v;
}

// compress frags: bid = w*8+f; wave w -> out cols w*16..+15; f = k/32 (0..7)
__global__ __launch_bounds__(512) void k_prep_wcp(
    const float* __restrict__ Wc, _Float16* __restrict__ WcP)
{
    int bid = blockIdx.x;               // 64
    int w = bid >> 3, f = bid & 7;
    int t = threadIdx.x;
    int l = t >> 3, e = t & 7;
    int oc = w*16 + (l & 15);
    int k = f*32 + (l >> 4)*8 + e;
    WcP[(ull)bid*512 + t] = (_Float16)Wc[oc*256 + k];
}

__global__ __launch_bounds__(256) void k_prep_bias(
    const float* __restrict__ b_ih, const float* __restrict__ b_hh,
    const float* __restrict__ W_ih, const float* __restrict__ be,
    float* __restrict__ biasG)
{
    int row = blockIdx.x*256 + threadIdx.x;   // 1024
    int g = row >> 8, c = row & 255;
    float v;
    if (g < 3) {
        int r = g*256 + c;
        float bx = b_ih[r];
        #pragma unroll 4
        for (int e = 0; e < 128; ++e) bx = fmaf(W_ih[r*128 + e], be[e], bx);
        v = (g == 0) ? bx + b_hh[c] : (g == 1) ? bx + b_hh[256 + c] : bx;
    } else v = b_hh[512 + c];
    biasG[row] = v;
}

__global__ __launch_bounds__(256) void k_prep_x(
    const float* __restrict__ x, _Float16* __restrict__ xH)
{
    int cell = blockIdx.x;              // 1024
    int i = cell >> 5, j = cell & 31;
    int b = threadIdx.x >> 2, k16 = (threadIdx.x & 3)*16;
    const float* src = &x[((b*32 + i)*32 + j)*64 + k16];
    _Float16* dst = &xH[((ull)cell*64 + b)*64 + k16];
    #pragma unroll
    for (int kk = 0; kk < 16; kk += 4) {
        float4 v = *(const float4*)&src[kk];
        dst[kk+0] = (_Float16)v.x; dst[kk+1] = (_Float16)v.y;
        dst[kk+2] = (_Float16)v.z; dst[kk+3] = (_Float16)v.w;
    }
}

// -------- persistent 2D-GRU: ch-split + PARTIAL COMPRESS (one exchange/cell)
// 64 WGs x 512 thr. WG (i=blk>>1, s=blk&1): row i, gate channels s*128..+127.
// Exports only its compress PARTIAL (K = own 128 hnew ch); consumers sum the
// two partials during staging. No intra-cell partner exchange.
__global__ void __launch_bounds__(512, 2)
k_grid(char* __restrict__ wsb, const float* __restrict__ bcb, float* __restrict__ out)
{
    const _Float16* WtP = (const _Float16*)(wsb + OFF_WTP);
    const _Float16* WcP = (const _Float16*)(wsb + OFF_WCP);
    const float*  biasG = (const float*)(wsb + OFF_BIASG);
    const _Float16* xH  = (const _Float16*)(wsb + OFF_XH);
    _Float16* hcP = (_Float16*)(wsb + OFF_HCP);
    int* flags = (int*)(wsb + OFF_FLAGS);

    __shared__ __align__(16) _Float16 As[64][328];  // [b][k 0..319]; cols reused as hnew
    __shared__ __align__(16) _Float16 hcO[64][136]; // own compress partial (persists j->j+1)

    const int blk = blockIdx.x;
    const int i = blk >> 1, s = blk & 1;
    const int tid = threadIdx.x;
    const int w = tid >> 6, l = tid & 63;
    const int l15 = l & 15, lhi = l >> 4;
    const int ko = lhi*8;
    const int c = s*128 + w*16 + l15;              // gate channel
    const int b8 = tid >> 3, q8 = tid & 7;         // staging decomposition

    const float bi0 = biasG[c],       bi1 = biasG[256 + c];
    const float bi2 = biasG[512 + c], bi3 = biasG[768 + c];
    // compress: every wave owns out cols w*16..+15, K = own half (4 frags)
    const int oc = w*16 + l15;
    const float bcv = (s == 0) ? bcb[oc] : 0.f;    // bias only in s=0 partial
    half8 wcr[4];
    #pragma unroll
    for (int fl = 0; fl < 4; ++fl)
        wcr[fl] = *(const half8*)&WcP[((ull)(w*8 + s*4 + fl))*512 + l*8];
    const _Float16* WtPw = WtP + ((ull)(s*8 + w)*30)*512 + l*8;   // frag f at +f*512

    for (int j = 0; j < 32; ++j) {
        // x prefetch (independent of deps)
        uint4 xv = *(const uint4*)&xH[((ull)(i*32 + j)*64 + b8)*64 + q8*8];
        // ---- dependency polls (ALL threads; no barrier+wake chain) ----
        if (i > 0) {
            while (ldrlx(flags + (2*(i-1)    )*64) < j + 1) __builtin_amdgcn_s_sleep(2);
            while (ldrlx(flags + (2*(i-1) + 1)*64) < j + 1) __builtin_amdgcn_s_sleep(2);
        }
        if (j > 0)
            while (ldrlx(flags + (2*i + 1 - s)*64) < j) __builtin_amdgcn_s_sleep(2);

        // ---- stage A: x | (p0+p1 row-above) | (own LDS + partner MALL col) ----
        *(uint4*)&As[b8][q8*8] = xv;
        if (i > 0) {
            const _Float16* p0 = hcP + ((ull)(((0*2 + ((i-1)&1))*32 + j)*64 + b8))*128 + q8*16;
            const _Float16* p1 = hcP + ((ull)(((1*2 + ((i-1)&1))*32 + j)*64 + b8))*128 + q8*16;
            half8 v0, v1, u0, u1;
            *(ull*)&v0       = ald64(p0);      *((ull*)&v0 + 1) = ald64(p0 + 4);
            *(ull*)&v1       = ald64(p0 + 8);  *((ull*)&v1 + 1) = ald64(p0 + 12);
            *(ull*)&u0       = ald64(p1);      *((ull*)&u0 + 1) = ald64(p1 + 4);
            *(ull*)&u1       = ald64(p1 + 8);  *((ull*)&u1 + 1) = ald64(p1 + 12);
            *(half8*)&As[b8][64 + q8*16]     = v0 + u0;
            *(half8*)&As[b8][64 + q8*16 + 8] = v1 + u1;
        } else {
            half8 hz = {};
            *(half8*)&As[b8][64 + q8*16]     = hz;
            *(half8*)&As[b8][64 + q8*16 + 8] = hz;
        }
        if (j > 0) {
            const _Float16* pp = hcP + ((ull)((((1-s)*2 + (i&1))*32 + (j-1))*64 + b8))*128 + q8*16;
            half8 m0, m1;
            *(ull*)&m0       = ald64(pp);      *((ull*)&m0 + 1) = ald64(pp + 4);
            *(ull*)&m1       = ald64(pp + 8);  *((ull*)&m1 + 1) = ald64(pp + 12);
            half8 o0 = *(const half8*)&hcO[b8][q8*16];
            half8 o1 = *(const half8*)&hcO[b8][q8*16 + 8];
            *(half8*)&As[b8][192 + q8*16]     = o0 + m0;
            *(half8*)&As[b8][192 + q8*16 + 8] = o1 + m1;
        } else {
            half8 hz = {};
            *(half8*)&As[b8][192 + q8*16]     = hz;
            *(half8*)&As[b8][192 + q8*16 + 8] = hz;
        }
        __syncthreads();   // S2: A staged

        // ---- gate GEMM: single m-pass, M=64, 16 ch/wave, K=320 (30 frags) ----
        f32x4 g0[4], g1[4], g2[4], g3[4];
        #pragma unroll
        for (int m = 0; m < 4; ++m) {
            g0[m] = (f32x4){bi0, bi0, bi0, bi0};
            g1[m] = (f32x4){bi1, bi1, bi1, bi1};
            g2[m] = (f32x4){bi2, bi2, bi2, bi2};
            g3[m] = (f32x4){bi3, bi3, bi3, bi3};
        }
        #pragma unroll
        for (int ks = 0; ks < 10; ++ks) {
            half8 a0 = *(const half8*)&As[     l15][ks*32 + ko];
            half8 a1 = *(const half8*)&As[16 + l15][ks*32 + ko];
            half8 a2 = *(const half8*)&As[32 + l15][ks*32 + ko];
            half8 a3 = *(const half8*)&As[48 + l15][ks*32 + ko];
            half8 b0 = *(const half8*)&WtPw[(ull)(     ks)*512];
            half8 b1 = *(const half8*)&WtPw[(ull)(10 + ks)*512];
            half8 b2 = *(const half8*)&WtPw[(ull)(20 + ks)*512];
            g0[0] = __builtin_amdgcn_mfma_f32_16x16x32_f16(a0, b0, g0[0], 0,0,0);
            g0[1] = __builtin_amdgcn_mfma_f32_16x16x32_f16(a1, b0, g0[1], 0,0,0);
            g0[2] = __builtin_amdgcn_mfma_f32_16x16x32_f16(a2, b0, g0[2], 0,0,0);
            g0[3] = __builtin_amdgcn_mfma_f32_16x16x32_f16(a3, b0, g0[3], 0,0,0);
            g1[0] = __builtin_amdgcn_mfma_f32_16x16x32_f16(a0, b1, g1[0], 0,0,0);
            g1[1] = __builtin_amdgcn_mfma_f32_16x16x32_f16(a1, b1, g1[1], 0,0,0);
            g1[2] = __builtin_amdgcn_mfma_f32_16x16x32_f16(a2, b1, g1[2], 0,0,0);
            g1[3] = __builtin_amdgcn_mfma_f32_16x16x32_f16(a3, b1, g1[3], 0,0,0);
            if (ks < 2) {
                g2[0] = __builtin_amdgcn_mfma_f32_16x16x32_f16(a0, b2, g2[0], 0,0,0);
                g2[1] = __builtin_amdgcn_mfma_f32_16x16x32_f16(a1, b2, g2[1], 0,0,0);
                g2[2] = __builtin_amdgcn_mfma_f32_16x16x32_f16(a2, b2, g2[2], 0,0,0);
                g2[3] = __builtin_amdgcn_mfma_f32_16x16x32_f16(a3, b2, g2[3], 0,0,0);
            } else {
                g3[0] = __builtin_amdgcn_mfma_f32_16x16x32_f16(a0, b2, g3[0], 0,0,0);
                g3[1] = __builtin_amdgcn_mfma_f32_16x16x32_f16(a1, b2, g3[1], 0,0,0);
                g3[2] = __builtin_amdgcn_mfma_f32_16x16x32_f16(a2, b2, g3[2], 0,0,0);
                g3[3] = __builtin_amdgcn_mfma_f32_16x16x32_f16(a3, b2, g3[3], 0,0,0);
            }
        }
        // ---- gate nonlinearities (blend hval from staged fp16 A) ----
        float hn[4][4];
        #pragma unroll
        for (int m = 0; m < 4; ++m) {
            #pragma unroll
            for (int r = 0; r < 4; ++r) {
                const int row = m*16 + lhi*4 + r;
                float rg = 1.f/(1.f + __expf(-g0[m][r]));
                float zg = 1.f/(1.f + __expf(-g1[m][r]));
                float e2 = __expf(2.f*(g2[m][r] + rg*g3[m][r]));
                float ng = 1.f - 2.f/(e2 + 1.f);
                float hv = (float)As[row][(s ? 192 : 64) + w*16 + l15];
                hn[m][r] = (1.f - zg)*ng + zg*hv;
            }
        }
        __syncthreads();   // S3: all A reads (GEMM + blend) done
        #pragma unroll
        for (int m = 0; m < 4; ++m)
            #pragma unroll
            for (int r = 0; r < 4; ++r)
                As[m*16 + lhi*4 + r][c] = (_Float16)hn[m][r];
        __syncthreads();   // S4: hnew (own half) in LDS
        // ---- compress PARTIAL: K = own 128 ch; all 8 waves, 16 cols each ----
        f32x4 cc[4];
        #pragma unroll
        for (int m = 0; m < 4; ++m) cc[m] = (f32x4){bcv, bcv, bcv, bcv};
        #pragma unroll
        for (int fl = 0; fl < 4; ++fl) {
            #pragma unroll
            for (int m = 0; m < 4; ++m) {
                half8 a = *(const half8*)&As[m*16 + l15][s*128 + fl*32 + ko];
                cc[m] = __builtin_amdgcn_mfma_f32_16x16x32_f16(a, wcr[fl], cc[m], 0,0,0);
            }
        }
        #pragma unroll
        for (int m = 0; m < 4; ++m)
            #pragma unroll
            for (int r = 0; r < 4; ++r)
                hcO[m*16 + lhi*4 + r][oc] = (_Float16)cc[m][r];
        __syncthreads();   // S5: hcO complete
        // ---- export partial (relaxed sc1 -> MALL) ----
        {
            _Float16* dst = hcP + ((ull)(((s*2 + (i&1))*32 + j)*64 + b8))*128 + q8*16;
            ast64(dst,      *(const ull*)&hcO[b8][q8*16]);
            ast64(dst + 4,  *(const ull*)&hcO[b8][q8*16 + 4]);
            ast64(dst + 8,  *(const ull*)&hcO[b8][q8*16 + 8]);
            ast64(dst + 12, *(const ull*)&hcO[b8][q8*16 + 12]);
        }
        __syncthreads();   // S6: all waves' stores drained (vmcnt0 at barrier)
        if (tid == 0) astrlx(flags + blk*64, j + 1);
    }

    // ---- final output: blk 63 sums its partial with blk 62's ----
    if (blk == 63) {
        while (ldrlx(flags + 62*64) < 32) __builtin_amdgcn_s_sleep(2);
        const _Float16* p0 = hcP + ((ull)(((0*2 + 1)*32 + 31)*64 + b8))*128 + q8*16;
        half8 v0, v1;
        *(ull*)&v0       = ald64(p0);      *((ull*)&v0 + 1) = ald64(p0 + 4);
        *(ull*)&v1       = ald64(p0 + 8);  *((ull*)&v1 + 1) = ald64(p0 + 12);
        float* od = out + b8*128 + q8*16;
        #pragma unroll
        for (int e = 0; e < 8; ++e) {
            od[e]     = (float)v0[e] + (float)hcO[b8][q8*16 + e];
            od[e + 8] = (float)v1[e] + (float)hcO[b8][q8*16 + 8 + e];
        }
    }
}

extern "C" void kernel_launch(void* const* d_in, const int* in_sizes, int n_in,
                              void* d_out, int out_size, void* d_ws, size_t ws_size,
                              hipStream_t stream)
{
    const float* x    = (const float*)d_in[0];
    const float* We   = (const float*)d_in[1];
    const float* be   = (const float*)d_in[2];
    const float* W_ih = (const float*)d_in[3];
    const float* b_ih = (const float*)d_in[4];
    const float* W_hh = (const float*)d_in[5];
    const float* b_hh = (const float*)d_in[6];
    const float* Wc   = (const float*)d_in[7];
    const float* bc   = (const float*)d_in[8];
    char* wsb = (char*)d_ws;
    float* Wx     = (float*)(wsb + OFF_WX);
    _Float16* WtP = (_Float16*)(wsb + OFF_WTP);
    _Float16* WcP = (_Float16*)(wsb + OFF_WCP);
    float* biasG  = (float*)(wsb + OFF_BIASG);
    _Float16* xH  = (_Float16*)(wsb + OFF_XH);
    int* flags    = (int*)(wsb + OFF_FLAGS);
    float* out    = (float*)d_out;

    k_build_wx<<<192, 256, 0, stream>>>(W_ih, We, Wx);
    k_prep_wtp<<<480, 512, 0, stream>>>(Wx, W_hh, WtP);
    k_prep_wcp<<<64, 512, 0, stream>>>(Wc, WcP);
    k_prep_bias<<<4, 256, 0, stream>>>(b_ih, b_hh, W_ih, be, biasG);
    k_prep_x<<<1024, 256, 0, stream>>>(x, xH);
    hipMemsetAsync(flags, 0, 64*64*sizeof(int), stream);
    k_grid<<<64, 512, 0, stream>>>(wsb, bc, out);
}

// Round 9
// 622.757 us; speedup vs baseline: 2.0018x; 1.0549x over previous
//
#include <hip/hip_runtime.h>

typedef _Float16 half8 __attribute__((ext_vector_type(8)));
typedef _Float16 half4 __attribute__((ext_vector_type(4)));
typedef float f32x4 __attribute__((ext_vector_type(4)));
typedef unsigned long long ull;

// ---- ws layout (byte offsets) ----
#define OFF_WTP   0u          // WtP fp16 gate frags [16 slots][30 frags][512] = 491520
#define OFF_WCP   491520u     // WcP fp16 compress frags [8 w][8 f][512] = 65536
#define OFF_BIASG 557056u     // biasG f32 [1024] = 4096
#define OFF_WX    561152u     // Wx f32 [768][64] = 196608
#define OFF_XH    757760u     // xH fp16 [1024][64][64] = 8388608
#define OFF_HCP   9146368u    // hcP fp16 [2 s][2 ip][32 j][8192] = 2097152 (plane-major cells)
#define OFF_FLAGS 11243520u   // CF[64] x 64-int pad = 16384

// ---- coherent helpers: relaxed agent-scope only (sc1 -> MALL), no acq/rel --
__device__ __forceinline__ int ldrlx(const int* p) {
    return __hip_atomic_load(p, __ATOMIC_RELAXED, __HIP_MEMORY_SCOPE_AGENT);
}
__device__ __forceinline__ void astrlx(int* p, int v) {
    __hip_atomic_store(p, v, __ATOMIC_RELAXED, __HIP_MEMORY_SCOPE_AGENT);
}
__device__ __forceinline__ ull ald64(const void* p) {
    return __hip_atomic_load((const ull*)p, __ATOMIC_RELAXED, __HIP_MEMORY_SCOPE_AGENT);
}
__device__ __forceinline__ void ast64(void* p, ull v) {
    __hip_atomic_store((ull*)p, v, __ATOMIC_RELAXED, __HIP_MEMORY_SCOPE_AGENT);
}
union U64H { ull u; half4 h; };

// ---------------- prep kernels (r8-proven) ----------------
__global__ __launch_bounds__(256) void k_build_wx(
    const float* __restrict__ W_ih, const float* __restrict__ We,
    float* __restrict__ Wx)
{
    __shared__ float WeS[128][64];
    const int tid = threadIdx.x;
    #pragma unroll
    for (int q = 0; q < 8; ++q) {
        int p = q*256 + tid;
        int e = p >> 4, k4 = p & 15;
        *(float4*)&WeS[e][k4*4] = *(const float4*)&We[e*64 + k4*4];
    }
    __syncthreads();
    int idx = blockIdx.x*256 + tid;     // 49152 -> 192 blocks
    int r = idx >> 6, k = idx & 63;
    float acc = 0.f;
    #pragma unroll 4
    for (int e = 0; e < 128; ++e) acc = fmaf(W_ih[r*128 + e], WeS[e][k], acc);
    Wx[idx] = acc;
}

__global__ __launch_bounds__(512) void k_prep_wtp(
    const float* __restrict__ Wx, const float* __restrict__ W_hh,
    _Float16* __restrict__ WtP)
{
    int bid = blockIdx.x;               // 480 = 16 slots * 30 frags
    int sw = bid / 30, f = bid % 30;
    int s = sw >> 3, w = sw & 7;
    int t = threadIdx.x;
    int l = t >> 3, e = t & 7;
    int g, ks;
    if (f < 10)      { g = 0; ks = f; }
    else if (f < 20) { g = 1; ks = f - 10; }
    else if (f < 22) { g = 2; ks = f - 20; }
    else             { g = 3; ks = f - 20; }
    int c = s*128 + w*16 + (l & 15);
    int k = ks*32 + (l >> 4)*8 + e;
    float v;
    if (k < 64) v = Wx[(g*256 + c)*64 + k];
    else {
        int rr = (g == 3) ? (512 + c) : (g*256 + c);
        v = W_hh[rr*256 + (k - 64)];
    }
    WtP[(ull)bid*512 + t] = (_Float16)v;
}

__global__ __launch_bounds__(512) void k_prep_wcp(
    const float* __restrict__ Wc, _Float16* __restrict__ WcP)
{
    int bid = blockIdx.x;               // 64
    int w = bid >> 3, f = bid & 7;
    int t = threadIdx.x;
    int l = t >> 3, e = t & 7;
    int oc = w*16 + (l & 15);
    int k = f*32 + (l >> 4)*8 + e;
    WcP[(ull)bid*512 + t] = (_Float16)Wc[oc*256 + k];
}

__global__ __launch_bounds__(256) void k_prep_bias(
    const float* __restrict__ b_ih, const float* __restrict__ b_hh,
    const float* __restrict__ W_ih, const float* __restrict__ be,
    float* __restrict__ biasG)
{
    int row = blockIdx.x*256 + threadIdx.x;   // 1024
    int g = row >> 8, c = row & 255;
    float v;
    if (g < 3) {
        int r = g*256 + c;
        float bx = b_ih[r];
        #pragma unroll 4
        for (int e = 0; e < 128; ++e) bx = fmaf(W_ih[r*128 + e], be[e], bx);
        v = (g == 0) ? bx + b_hh[c] : (g == 1) ? bx + b_hh[256 + c] : bx;
    } else v = b_hh[512 + c];
    biasG[row] = v;
}

__global__ __launch_bounds__(256) void k_prep_x(
    const float* __restrict__ x, _Float16* __restrict__ xH)
{
    int cell = blockIdx.x;              // 1024
    int i = cell >> 5, j = cell & 31;
    int b = threadIdx.x >> 2, k16 = (threadIdx.x & 3)*16;
    const float* src = &x[((b*32 + i)*32 + j)*64 + k16];
    _Float16* dst = &xH[((ull)cell*64 + b)*64 + k16];
    #pragma unroll
    for (int kk = 0; kk < 16; kk += 4) {
        float4 v = *(const float4*)&src[kk];
        dst[kk+0] = (_Float16)v.x; dst[kk+1] = (_Float16)v.y;
        dst[kk+2] = (_Float16)v.z; dst[kk+3] = (_Float16)v.w;
    }
}

// -------- persistent 2D-GRU: ch-split, register-resident weights,
//          plane-major MALL handoff. 64 WGs x 512 thr; WG (i, s).
__global__ void __launch_bounds__(512, 2)
k_grid(char* __restrict__ wsb, const float* __restrict__ bcb, float* __restrict__ out)
{
    const _Float16* WtP = (const _Float16*)(wsb + OFF_WTP);
    const _Float16* WcP = (const _Float16*)(wsb + OFF_WCP);
    const float*  biasG = (const float*)(wsb + OFF_BIASG);
    const _Float16* xH  = (const _Float16*)(wsb + OFF_XH);
    _Float16* hcP = (_Float16*)(wsb + OFF_HCP);
    int* flags = (int*)(wsb + OFF_FLAGS);

    __shared__ __align__(16) _Float16 As[64][328];  // [b][k 0..319]; cols 0..255 reused as hnew
    __shared__ __align__(16) _Float16 hcO[64][136]; // own compress partial (persists j->j+1)

    const int blk = blockIdx.x;
    const int i = blk >> 1, s = blk & 1;
    const int tid = threadIdx.x;
    const int w = tid >> 6, l = tid & 63;
    const int l15 = l & 15, lhi = l >> 4;
    const int ko = lhi*8;
    const int c = s*128 + w*16 + l15;              // gate channel
    const int b8 = tid >> 3, q8 = tid & 7;         // x staging decomposition
    // plane-major handoff mapping: plane k, thread t -> half-index k*2048+t*4
    const int pb = tid >> 5;                        // b within plane-chunk: b = k*16 + pb
    const int pc = (tid & 31)*4;                    // channel offset 0..124

    const float bi0 = biasG[c],       bi1 = biasG[256 + c];
    const float bi2 = biasG[512 + c], bi3 = biasG[768 + c];
    const int oc = w*16 + l15;
    const float bcv = (s == 0) ? bcb[oc] : 0.f;
    half8 wcr0, wcr1, wcr2, wcr3;
    {
        const _Float16* Wcp = WcP + ((ull)(w*8 + s*4))*512 + l*8;
        wcr0 = *(const half8*)&Wcp[0];
        wcr1 = *(const half8*)&Wcp[512];
        wcr2 = *(const half8*)&Wcp[1024];
        wcr3 = *(const half8*)&Wcp[1536];
    }
    // ---- 30 gate B-frags as NAMED registers (120 VGPR, loaded once) ----
    const _Float16* Wp = WtP + ((ull)(s*8 + w)*30)*512 + (ull)l*8;
#define LW(f) (*(const half8*)&Wp[(ull)(f)*512])
    half8 b0_0=LW(0), b0_1=LW(1), b0_2=LW(2), b0_3=LW(3), b0_4=LW(4);
    half8 b0_5=LW(5), b0_6=LW(6), b0_7=LW(7), b0_8=LW(8), b0_9=LW(9);
    half8 b1_0=LW(10), b1_1=LW(11), b1_2=LW(12), b1_3=LW(13), b1_4=LW(14);
    half8 b1_5=LW(15), b1_6=LW(16), b1_7=LW(17), b1_8=LW(18), b1_9=LW(19);
    half8 b2_0=LW(20), b2_1=LW(21);
    half8 b3_2=LW(22), b3_3=LW(23), b3_4=LW(24), b3_5=LW(25);
    half8 b3_6=LW(26), b3_7=LW(27), b3_8=LW(28), b3_9=LW(29);
#undef LW

    for (int j = 0; j < 32; ++j) {
        // x prefetch (independent of deps)
        uint4 xv = *(const uint4*)&xH[((ull)(i*32 + j)*64 + b8)*64 + q8*8];
        // ---- dependency polls (all threads) ----
        if (i > 0) {
            const int* f0 = flags + (2*(i-1))*64;
            while (ldrlx(f0) <= j || ldrlx(f0 + 64) <= j) __builtin_amdgcn_s_sleep(1);
        }
        if (j > 0)
            while (ldrlx(flags + (2*i + 1 - s)*64) < j) __builtin_amdgcn_s_sleep(1);

        // ---- stage A: x | (p0+p1 row-above) | (own hcO + partner) ----
        *(uint4*)&As[b8][q8*8] = xv;
        if (i > 0) {
            const _Float16* p0 = hcP + ((ull)((0*2 + ((i-1)&1))*32 + j))*8192 + tid*4;
            const _Float16* p1 = p0 + 2*32*8192;   // s=1 block
            #pragma unroll
            for (int k = 0; k < 4; ++k) {
                U64H a, b2; a.u = ald64(p0 + k*2048); b2.u = ald64(p1 + k*2048);
                *(half4*)&As[k*16 + pb][64 + pc] = a.h + b2.h;
            }
        } else {
            #pragma unroll
            for (int k = 0; k < 4; ++k)
                *(half4*)&As[k*16 + pb][64 + pc] = (half4){};
        }
        if (j > 0) {
            const _Float16* pp = hcP + ((ull)(((1-s)*2 + (i&1))*32 + (j-1)))*8192 + tid*4;
            #pragma unroll
            for (int k = 0; k < 4; ++k) {
                U64H m; m.u = ald64(pp + k*2048);
                half4 own = *(const half4*)&hcO[k*16 + pb][pc];
                *(half4*)&As[k*16 + pb][192 + pc] = own + m.h;
            }
        } else {
            #pragma unroll
            for (int k = 0; k < 4; ++k)
                *(half4*)&As[k*16 + pb][192 + pc] = (half4){};
        }
        __syncthreads();   // S2: A staged

        // ---- gate GEMM: 2 m-passes, register B, LDS A ----
        #pragma unroll
        for (int mp = 0; mp < 2; ++mp) {
            f32x4 g00 = {bi0,bi0,bi0,bi0}, g01 = {bi0,bi0,bi0,bi0};
            f32x4 g10 = {bi1,bi1,bi1,bi1}, g11 = {bi1,bi1,bi1,bi1};
            f32x4 g20 = {bi2,bi2,bi2,bi2}, g21 = {bi2,bi2,bi2,bi2};
            f32x4 g30 = {bi3,bi3,bi3,bi3}, g31 = {bi3,bi3,bi3,bi3};
#define GX(ks, B0, B1, B2) do { \
    half8 a0 = *(const half8*)&As[mp*32 +      l15][(ks)*32 + ko]; \
    half8 a1 = *(const half8*)&As[mp*32 + 16 + l15][(ks)*32 + ko]; \
    g00 = __builtin_amdgcn_mfma_f32_16x16x32_f16(a0, B0, g00, 0,0,0); \
    g01 = __builtin_amdgcn_mfma_f32_16x16x32_f16(a1, B0, g01, 0,0,0); \
    g10 = __builtin_amdgcn_mfma_f32_16x16x32_f16(a0, B1, g10, 0,0,0); \
    g11 = __builtin_amdgcn_mfma_f32_16x16x32_f16(a1, B1, g11, 0,0,0); \
    g20 = __builtin_amdgcn_mfma_f32_16x16x32_f16(a0, B2, g20, 0,0,0); \
    g21 = __builtin_amdgcn_mfma_f32_16x16x32_f16(a1, B2, g21, 0,0,0); } while(0)
#define GH(ks, B0, B1, B3) do { \
    half8 a0 = *(const half8*)&As[mp*32 +      l15][(ks)*32 + ko]; \
    half8 a1 = *(const half8*)&As[mp*32 + 16 + l15][(ks)*32 + ko]; \
    g00 = __builtin_amdgcn_mfma_f32_16x16x32_f16(a0, B0, g00, 0,0,0); \
    g01 = __builtin_amdgcn_mfma_f32_16x16x32_f16(a1, B0, g01, 0,0,0); \
    g10 = __builtin_amdgcn_mfma_f32_16x16x32_f16(a0, B1, g10, 0,0,0); \
    g11 = __builtin_amdgcn_mfma_f32_16x16x32_f16(a1, B1, g11, 0,0,0); \
    g30 = __builtin_amdgcn_mfma_f32_16x16x32_f16(a0, B3, g30, 0,0,0); \
    g31 = __builtin_amdgcn_mfma_f32_16x16x32_f16(a1, B3, g31, 0,0,0); } while(0)
            GX(0, b0_0, b1_0, b2_0);
            GX(1, b0_1, b1_1, b2_1);
            GH(2, b0_2, b1_2, b3_2);
            GH(3, b0_3, b1_3, b3_3);
            GH(4, b0_4, b1_4, b3_4);
            GH(5, b0_5, b1_5, b3_5);
            GH(6, b0_6, b1_6, b3_6);
            GH(7, b0_7, b1_7, b3_7);
            GH(8, b0_8, b1_8, b3_8);
            GH(9, b0_9, b1_9, b3_9);
#undef GX
#undef GH
            // ---- nonlinearities for this m-pass ----
            float hn0[4], hn1[4];
            #pragma unroll
            for (int r = 0; r < 4; ++r) {
                const int row0 = mp*32 + lhi*4 + r;
                float rg = 1.f/(1.f + __expf(-g00[r]));
                float zg = 1.f/(1.f + __expf(-g10[r]));
                float e2 = __expf(2.f*(g20[r] + rg*g30[r]));
                float ng = 1.f - 2.f/(e2 + 1.f);
                float hv = (float)As[row0][(s ? 192 : 64) + w*16 + l15];
                hn0[r] = (1.f - zg)*ng + zg*hv;
                const int row1 = row0 + 16;
                float rg1 = 1.f/(1.f + __expf(-g01[r]));
                float zg1 = 1.f/(1.f + __expf(-g11[r]));
                float e21 = __expf(2.f*(g21[r] + rg1*g31[r]));
                float ng1 = 1.f - 2.f/(e21 + 1.f);
                float hv1 = (float)As[row1][(s ? 192 : 64) + w*16 + l15];
                hn1[r] = (1.f - zg1)*ng1 + zg1*hv1;
            }
            __syncthreads();   // S3: this pass's A/blend reads done
            #pragma unroll
            for (int r = 0; r < 4; ++r) {
                As[mp*32 +      lhi*4 + r][c] = (_Float16)hn0[r];
                As[mp*32 + 16 + lhi*4 + r][c] = (_Float16)hn1[r];
            }
        }
        __syncthreads();   // S4: hnew complete in LDS
        // ---- compress PARTIAL (K = own 128 ch), register Wc ----
        f32x4 cc0 = {bcv,bcv,bcv,bcv}, cc1 = cc0, cc2 = cc0, cc3 = cc0;
#define CSTEP(fl, WF) do { \
    half8 a0 = *(const half8*)&As[     l15][s*128 + (fl)*32 + ko]; \
    half8 a1 = *(const half8*)&As[16 + l15][s*128 + (fl)*32 + ko]; \
    half8 a2 = *(const half8*)&As[32 + l15][s*128 + (fl)*32 + ko]; \
    half8 a3 = *(const half8*)&As[48 + l15][s*128 + (fl)*32 + ko]; \
    cc0 = __builtin_amdgcn_mfma_f32_16x16x32_f16(a0, WF, cc0, 0,0,0); \
    cc1 = __builtin_amdgcn_mfma_f32_16x16x32_f16(a1, WF, cc1, 0,0,0); \
    cc2 = __builtin_amdgcn_mfma_f32_16x16x32_f16(a2, WF, cc2, 0,0,0); \
    cc3 = __builtin_amdgcn_mfma_f32_16x16x32_f16(a3, WF, cc3, 0,0,0); } while(0)
        CSTEP(0, wcr0); CSTEP(1, wcr1); CSTEP(2, wcr2); CSTEP(3, wcr3);
#undef CSTEP
        #pragma unroll
        for (int r = 0; r < 4; ++r) {
            hcO[     lhi*4 + r][oc] = (_Float16)cc0[r];
            hcO[16 + lhi*4 + r][oc] = (_Float16)cc1[r];
            hcO[32 + lhi*4 + r][oc] = (_Float16)cc2[r];
            hcO[48 + lhi*4 + r][oc] = (_Float16)cc3[r];
        }
        __syncthreads();   // S5: hcO complete
        // ---- export partial, plane-major dense (relaxed sc1 -> MALL) ----
        {
            _Float16* dst = hcP + ((ull)((s*2 + (i&1))*32 + j))*8192 + tid*4;
            #pragma unroll
            for (int k = 0; k < 4; ++k)
                ast64(dst + k*2048, *(const ull*)&hcO[k*16 + pb][pc]);
        }
        __syncthreads();   // S6: all waves' stores drained (vmcnt0 at barrier)
        if (tid == 0) astrlx(flags + blk*64, j + 1);
    }

    // ---- final output: blk 63 (i=31,s=1) sums its partial with blk 62's ----
    if (blk == 63) {
        while (ldrlx(flags + 62*64) < 32) __builtin_amdgcn_s_sleep(1);
        const _Float16* p0 = hcP + ((ull)((0*2 + 1)*32 + 31))*8192 + tid*4;
        #pragma unroll
        for (int k = 0; k < 4; ++k) {
            U64H a; a.u = ald64(p0 + k*2048);
            half4 own = *(const half4*)&hcO[k*16 + pb][pc];
            float* od = out + (k*16 + pb)*128 + pc;
            #pragma unroll
            for (int e = 0; e < 4; ++e) od[e] = (float)a.h[e] + (float)own[e];
        }
    }
}

extern "C" void kernel_launch(void* const* d_in, const int* in_sizes, int n_in,
                              void* d_out, int out_size, void* d_ws, size_t ws_size,
                              hipStream_t stream)
{
    const float* x    = (const float*)d_in[0];
    const float* We   = (const float*)d_in[1];
    const float* be   = (const float*)d_in[2];
    const float* W_ih = (const float*)d_in[3];
    const float* b_ih = (const float*)d_in[4];
    const float* W_hh = (const float*)d_in[5];
    const float* b_hh = (const float*)d_in[6];
    const float* Wc   = (const float*)d_in[7];
    const float* bc   = (const float*)d_in[8];
    char* wsb = (char*)d_ws;
    float* Wx     = (float*)(wsb + OFF_WX);
    _Float16* WtP = (_Float16*)(wsb + OFF_WTP);
    _Float16* WcP = (_Float16*)(wsb + OFF_WCP);
    float* biasG  = (float*)(wsb + OFF_BIASG);
    _Float16* xH  = (_Float16*)(wsb + OFF_XH);
    int* flags    = (int*)(wsb + OFF_FLAGS);
    float* out    = (float*)d_out;

    k_build_wx<<<192, 256, 0, stream>>>(W_ih, We, Wx);
    k_prep_wtp<<<480, 512, 0, stream>>>(Wx, W_hh, WtP);
    k_prep_wcp<<<64, 512, 0, stream>>>(Wc, WcP);
    k_prep_bias<<<4, 256, 0, stream>>>(b_ih, b_hh, W_ih, be, biasG);
    k_prep_x<<<1024, 256, 0, stream>>>(x, xH);
    hipMemsetAsync(flags, 0, 64*64*sizeof(int), stream);
    k_grid<<<64, 512, 0, stream>>>(wsb, bc, out);
}

// Round 10
// 620.870 us; speedup vs baseline: 2.0079x; 1.0030x over previous
//
#include <hip/hip_runtime.h>

typedef _Float16 half8 __attribute__((ext_vector_type(8)));
typedef _Float16 half4 __attribute__((ext_vector_type(4)));
typedef float f32x4 __attribute__((ext_vector_type(4)));
typedef unsigned long long ull;

// ---- ws layout (byte offsets) ----
#define OFF_WTP   0u          // WtP fp16 gate frags [16 slots][30 frags][512] = 491520
#define OFF_WCP   491520u     // WcP fp16 compress frags [8 w][8 f][512] = 65536
#define OFF_BIASG 557056u     // biasG f32 [1024] = 4096
#define OFF_WX    561152u     // Wx f32 [768][64] = 196608
#define OFF_XH    757760u     // xH fp16 [1024][64][64] = 8388608
#define OFF_HCP   9146368u    // hcP fp16 [2 s][2 ip][32 j][8192] = 2097152 (plane-major cells)
#define OFF_FLAGS 11243520u   // CF[64] x 64-int pad = 16384

// ---- coherent helpers: relaxed agent-scope only (sc1 -> MALL), no acq/rel --
__device__ __forceinline__ int ldrlx(const int* p) {
    return __hip_atomic_load(p, __ATOMIC_RELAXED, __HIP_MEMORY_SCOPE_AGENT);
}
__device__ __forceinline__ void astrlx(int* p, int v) {
    __hip_atomic_store(p, v, __ATOMIC_RELAXED, __HIP_MEMORY_SCOPE_AGENT);
}
__device__ __forceinline__ ull ald64(const void* p) {
    return __hip_atomic_load((const ull*)p, __ATOMIC_RELAXED, __HIP_MEMORY_SCOPE_AGENT);
}
__device__ __forceinline__ void ast64(void* p, ull v) {
    __hip_atomic_store((ull*)p, v, __ATOMIC_RELAXED, __HIP_MEMORY_SCOPE_AGENT);
}
union U64H { ull u; half4 h; };

// ---------------- prep kernels (r8-proven) ----------------
__global__ __launch_bounds__(256) void k_build_wx(
    const float* __restrict__ W_ih, const float* __restrict__ We,
    float* __restrict__ Wx)
{
    __shared__ float WeS[128][64];
    const int tid = threadIdx.x;
    #pragma unroll
    for (int q = 0; q < 8; ++q) {
        int p = q*256 + tid;
        int e = p >> 4, k4 = p & 15;
        *(float4*)&WeS[e][k4*4] = *(const float4*)&We[e*64 + k4*4];
    }
    __syncthreads();
    int idx = blockIdx.x*256 + tid;     // 49152 -> 192 blocks
    int r = idx >> 6, k = idx & 63;
    float acc = 0.f;
    #pragma unroll 4
    for (int e = 0; e < 128; ++e) acc = fmaf(W_ih[r*128 + e], WeS[e][k], acc);
    Wx[idx] = acc;
}

__global__ __launch_bounds__(512) void k_prep_wtp(
    const float* __restrict__ Wx, const float* __restrict__ W_hh,
    _Float16* __restrict__ WtP)
{
    int bid = blockIdx.x;               // 480 = 16 slots * 30 frags
    int sw = bid / 30, f = bid % 30;
    int s = sw >> 3, w = sw & 7;
    int t = threadIdx.x;
    int l = t >> 3, e = t & 7;
    int g, ks;
    if (f < 10)      { g = 0; ks = f; }
    else if (f < 20) { g = 1; ks = f - 10; }
    else if (f < 22) { g = 2; ks = f - 20; }
    else             { g = 3; ks = f - 20; }
    int c = s*128 + w*16 + (l & 15);
    int k = ks*32 + (l >> 4)*8 + e;
    float v;
    if (k < 64) v = Wx[(g*256 + c)*64 + k];
    else {
        int rr = (g == 3) ? (512 + c) : (g*256 + c);
        v = W_hh[rr*256 + (k - 64)];
    }
    WtP[(ull)bid*512 + t] = (_Float16)v;
}

__global__ __launch_bounds__(512) void k_prep_wcp(
    const float* __restrict__ Wc, _Float16* __restrict__ WcP)
{
    int bid = blockIdx.x;               // 64
    int w = bid >> 3, f = bid & 7;
    int t = threadIdx.x;
    int l = t >> 3, e = t & 7;
    int oc = w*16 + (l & 15);
    int k = f*32 + (l >> 4)*8 + e;
    WcP[(ull)bid*512 + t] = (_Float16)Wc[oc*256 + k];
}

__global__ __launch_bounds__(256) void k_prep_bias(
    const float* __restrict__ b_ih, const float* __restrict__ b_hh,
    const float* __restrict__ W_ih, const float* __restrict__ be,
    float* __restrict__ biasG)
{
    int row = blockIdx.x*256 + threadIdx.x;   // 1024
    int g = row >> 8, c = row & 255;
    float v;
    if (g < 3) {
        int r = g*256 + c;
        float bx = b_ih[r];
        #pragma unroll 4
        for (int e = 0; e < 128; ++e) bx = fmaf(W_ih[r*128 + e], be[e], bx);
        v = (g == 0) ? bx + b_hh[c] : (g == 1) ? bx + b_hh[256 + c] : bx;
    } else v = b_hh[512 + c];
    biasG[row] = v;
}

__global__ __launch_bounds__(256) void k_prep_x(
    const float* __restrict__ x, _Float16* __restrict__ xH)
{
    int cell = blockIdx.x;              // 1024
    int i = cell >> 5, j = cell & 31;
    int b = threadIdx.x >> 2, k16 = (threadIdx.x & 3)*16;
    const float* src = &x[((b*32 + i)*32 + j)*64 + k16];
    _Float16* dst = &xH[((ull)cell*64 + b)*64 + k16];
    #pragma unroll
    for (int kk = 0; kk < 16; kk += 4) {
        float4 v = *(const float4*)&src[kk];
        dst[kk+0] = (_Float16)v.x; dst[kk+1] = (_Float16)v.y;
        dst[kk+2] = (_Float16)v.z; dst[kk+3] = (_Float16)v.w;
    }
}

// -------- persistent 2D-GRU: ch-split, ASM-PINNED register weights,
//          plane-major MALL handoff. 64 WGs x 512 thr; WG (i, s).
__global__ void __launch_bounds__(512, 2)
k_grid(char* __restrict__ wsb, const float* __restrict__ bcb, float* __restrict__ out)
{
    const _Float16* WtP = (const _Float16*)(wsb + OFF_WTP);
    const _Float16* WcP = (const _Float16*)(wsb + OFF_WCP);
    const float*  biasG = (const float*)(wsb + OFF_BIASG);
    const _Float16* xH  = (const _Float16*)(wsb + OFF_XH);
    _Float16* hcP = (_Float16*)(wsb + OFF_HCP);
    int* flags = (int*)(wsb + OFF_FLAGS);

    __shared__ __align__(16) _Float16 As[64][328];  // [b][k 0..319]; cols 0..255 reused as hnew
    __shared__ __align__(16) _Float16 hcO[64][136]; // own compress partial (persists j->j+1)

    const int blk = blockIdx.x;
    const int i = blk >> 1, s = blk & 1;
    const int tid = threadIdx.x;
    const int w = tid >> 6, l = tid & 63;
    const int l15 = l & 15, lhi = l >> 4;
    const int ko = lhi*8;
    const int c = s*128 + w*16 + l15;              // gate channel
    const int b8 = tid >> 3, q8 = tid & 7;         // x staging decomposition
    // plane-major handoff mapping: plane k, thread t -> half-index k*2048+t*4
    const int pb = tid >> 5;                        // b within plane-chunk: b = k*16 + pb
    const int pc = (tid & 31)*4;                    // channel offset 0..124

    const float bi0 = biasG[c],       bi1 = biasG[256 + c];
    const float bi2 = biasG[512 + c], bi3 = biasG[768 + c];
    const int oc = w*16 + l15;
    const float bcv = (s == 0) ? bcb[oc] : 0.f;
    half8 wcr0, wcr1, wcr2, wcr3;
    {
        const _Float16* Wcp = WcP + ((ull)(w*8 + s*4))*512 + l*8;
        wcr0 = *(const half8*)&Wcp[0];
        wcr1 = *(const half8*)&Wcp[512];
        wcr2 = *(const half8*)&Wcp[1024];
        wcr3 = *(const half8*)&Wcp[1536];
    }
    // ---- 30 gate B-frags, loaded once then PINNED via opaque asm so the
    //      allocator cannot rematerialize the loads inside the j-loop ----
    const _Float16* Wp = WtP + ((ull)(s*8 + w)*30)*512 + (ull)l*8;
#define LW(f) (*(const half8*)&Wp[(ull)(f)*512])
    half8 b0_0=LW(0), b0_1=LW(1), b0_2=LW(2), b0_3=LW(3), b0_4=LW(4);
    half8 b0_5=LW(5), b0_6=LW(6), b0_7=LW(7), b0_8=LW(8), b0_9=LW(9);
    half8 b1_0=LW(10), b1_1=LW(11), b1_2=LW(12), b1_3=LW(13), b1_4=LW(14);
    half8 b1_5=LW(15), b1_6=LW(16), b1_7=LW(17), b1_8=LW(18), b1_9=LW(19);
    half8 b2_0=LW(20), b2_1=LW(21);
    half8 b3_2=LW(22), b3_3=LW(23), b3_4=LW(24), b3_5=LW(25);
    half8 b3_6=LW(26), b3_7=LW(27), b3_8=LW(28), b3_9=LW(29);
#undef LW
    asm volatile("" : "+v"(b0_0), "+v"(b0_1), "+v"(b0_2), "+v"(b0_3), "+v"(b0_4),
                      "+v"(b0_5), "+v"(b0_6), "+v"(b0_7), "+v"(b0_8), "+v"(b0_9));
    asm volatile("" : "+v"(b1_0), "+v"(b1_1), "+v"(b1_2), "+v"(b1_3), "+v"(b1_4),
                      "+v"(b1_5), "+v"(b1_6), "+v"(b1_7), "+v"(b1_8), "+v"(b1_9));
    asm volatile("" : "+v"(b2_0), "+v"(b2_1),
                      "+v"(b3_2), "+v"(b3_3), "+v"(b3_4), "+v"(b3_5),
                      "+v"(b3_6), "+v"(b3_7), "+v"(b3_8), "+v"(b3_9));
    asm volatile("" : "+v"(wcr0), "+v"(wcr1), "+v"(wcr2), "+v"(wcr3));

    for (int j = 0; j < 32; ++j) {
        // x prefetch (independent of deps)
        uint4 xv = *(const uint4*)&xH[((ull)(i*32 + j)*64 + b8)*64 + q8*8];
        // ---- dependency polls (all threads) ----
        if (i > 0) {
            const int* f0 = flags + (2*(i-1))*64;
            while (ldrlx(f0) <= j || ldrlx(f0 + 64) <= j) __builtin_amdgcn_s_sleep(1);
        }
        if (j > 0)
            while (ldrlx(flags + (2*i + 1 - s)*64) < j) __builtin_amdgcn_s_sleep(1);

        // ---- stage A: x | (p0+p1 row-above) | (own hcO + partner) ----
        *(uint4*)&As[b8][q8*8] = xv;
        if (i > 0) {
            const _Float16* p0 = hcP + ((ull)((0*2 + ((i-1)&1))*32 + j))*8192 + tid*4;
            const _Float16* p1 = p0 + 2*32*8192;   // s=1 block
            #pragma unroll
            for (int k = 0; k < 4; ++k) {
                U64H a, b2; a.u = ald64(p0 + k*2048); b2.u = ald64(p1 + k*2048);
                *(half4*)&As[k*16 + pb][64 + pc] = a.h + b2.h;
            }
        } else {
            #pragma unroll
            for (int k = 0; k < 4; ++k)
                *(half4*)&As[k*16 + pb][64 + pc] = (half4){};
        }
        if (j > 0) {
            const _Float16* pp = hcP + ((ull)(((1-s)*2 + (i&1))*32 + (j-1)))*8192 + tid*4;
            #pragma unroll
            for (int k = 0; k < 4; ++k) {
                U64H m; m.u = ald64(pp + k*2048);
                half4 own = *(const half4*)&hcO[k*16 + pb][pc];
                *(half4*)&As[k*16 + pb][192 + pc] = own + m.h;
            }
        } else {
            #pragma unroll
            for (int k = 0; k < 4; ++k)
                *(half4*)&As[k*16 + pb][192 + pc] = (half4){};
        }
        __syncthreads();   // S2: A staged

        // ---- gate GEMM: 2 m-passes, pinned register B, LDS A ----
        #pragma unroll
        for (int mp = 0; mp < 2; ++mp) {
            f32x4 g00 = {bi0,bi0,bi0,bi0}, g01 = {bi0,bi0,bi0,bi0};
            f32x4 g10 = {bi1,bi1,bi1,bi1}, g11 = {bi1,bi1,bi1,bi1};
            f32x4 g20 = {bi2,bi2,bi2,bi2}, g21 = {bi2,bi2,bi2,bi2};
            f32x4 g30 = {bi3,bi3,bi3,bi3}, g31 = {bi3,bi3,bi3,bi3};
#define GX(ks, B0, B1, B2) do { \
    half8 a0 = *(const half8*)&As[mp*32 +      l15][(ks)*32 + ko]; \
    half8 a1 = *(const half8*)&As[mp*32 + 16 + l15][(ks)*32 + ko]; \
    g00 = __builtin_amdgcn_mfma_f32_16x16x32_f16(a0, B0, g00, 0,0,0); \
    g01 = __builtin_amdgcn_mfma_f32_16x16x32_f16(a1, B0, g01, 0,0,0); \
    g10 = __builtin_amdgcn_mfma_f32_16x16x32_f16(a0, B1, g10, 0,0,0); \
    g11 = __builtin_amdgcn_mfma_f32_16x16x32_f16(a1, B1, g11, 0,0,0); \
    g20 = __builtin_amdgcn_mfma_f32_16x16x32_f16(a0, B2, g20, 0,0,0); \
    g21 = __builtin_amdgcn_mfma_f32_16x16x32_f16(a1, B2, g21, 0,0,0); } while(0)
#define GH(ks, B0, B1, B3) do { \
    half8 a0 = *(const half8*)&As[mp*32 +      l15][(ks)*32 + ko]; \
    half8 a1 = *(const half8*)&As[mp*32 + 16 + l15][(ks)*32 + ko]; \
    g00 = __builtin_amdgcn_mfma_f32_16x16x32_f16(a0, B0, g00, 0,0,0); \
    g01 = __builtin_amdgcn_mfma_f32_16x16x32_f16(a1, B0, g01, 0,0,0); \
    g10 = __builtin_amdgcn_mfma_f32_16x16x32_f16(a0, B1, g10, 0,0,0); \
    g11 = __builtin_amdgcn_mfma_f32_16x16x32_f16(a1, B1, g11, 0,0,0); \
    g30 = __builtin_amdgcn_mfma_f32_16x16x32_f16(a0, B3, g30, 0,0,0); \
    g31 = __builtin_amdgcn_mfma_f32_16x16x32_f16(a1, B3, g31, 0,0,0); } while(0)
            GX(0, b0_0, b1_0, b2_0);
            GX(1, b0_1, b1_1, b2_1);
            GH(2, b0_2, b1_2, b3_2);
            GH(3, b0_3, b1_3, b3_3);
            GH(4, b0_4, b1_4, b3_4);
            GH(5, b0_5, b1_5, b3_5);
            GH(6, b0_6, b1_6, b3_6);
            GH(7, b0_7, b1_7, b3_7);
            GH(8, b0_8, b1_8, b3_8);
            GH(9, b0_9, b1_9, b3_9);
#undef GX
#undef GH
            // ---- nonlinearities for this m-pass ----
            float hn0[4], hn1[4];
            #pragma unroll
            for (int r = 0; r < 4; ++r) {
                const int row0 = mp*32 + lhi*4 + r;
                float rg = 1.f/(1.f + __expf(-g00[r]));
                float zg = 1.f/(1.f + __expf(-g10[r]));
                float e2 = __expf(2.f*(g20[r] + rg*g30[r]));
                float ng = 1.f - 2.f/(e2 + 1.f);
                float hv = (float)As[row0][(s ? 192 : 64) + w*16 + l15];
                hn0[r] = (1.f - zg)*ng + zg*hv;
                const int row1 = row0 + 16;
                float rg1 = 1.f/(1.f + __expf(-g01[r]));
                float zg1 = 1.f/(1.f + __expf(-g11[r]));
                float e21 = __expf(2.f*(g21[r] + rg1*g31[r]));
                float ng1 = 1.f - 2.f/(e21 + 1.f);
                float hv1 = (float)As[row1][(s ? 192 : 64) + w*16 + l15];
                hn1[r] = (1.f - zg1)*ng1 + zg1*hv1;
            }
            __syncthreads();   // S3: this pass's A/blend reads done
            #pragma unroll
            for (int r = 0; r < 4; ++r) {
                As[mp*32 +      lhi*4 + r][c] = (_Float16)hn0[r];
                As[mp*32 + 16 + lhi*4 + r][c] = (_Float16)hn1[r];
            }
        }
        __syncthreads();   // S4: hnew complete in LDS
        // ---- compress PARTIAL (K = own 128 ch), pinned register Wc ----
        f32x4 cc0 = {bcv,bcv,bcv,bcv}, cc1 = cc0, cc2 = cc0, cc3 = cc0;
#define CSTEP(fl, WF) do { \
    half8 a0 = *(const half8*)&As[     l15][s*128 + (fl)*32 + ko]; \
    half8 a1 = *(const half8*)&As[16 + l15][s*128 + (fl)*32 + ko]; \
    half8 a2 = *(const half8*)&As[32 + l15][s*128 + (fl)*32 + ko]; \
    half8 a3 = *(const half8*)&As[48 + l15][s*128 + (fl)*32 + ko]; \
    cc0 = __builtin_amdgcn_mfma_f32_16x16x32_f16(a0, WF, cc0, 0,0,0); \
    cc1 = __builtin_amdgcn_mfma_f32_16x16x32_f16(a1, WF, cc1, 0,0,0); \
    cc2 = __builtin_amdgcn_mfma_f32_16x16x32_f16(a2, WF, cc2, 0,0,0); \
    cc3 = __builtin_amdgcn_mfma_f32_16x16x32_f16(a3, WF, cc3, 0,0,0); } while(0)
        CSTEP(0, wcr0); CSTEP(1, wcr1); CSTEP(2, wcr2); CSTEP(3, wcr3);
#undef CSTEP
        #pragma unroll
        for (int r = 0; r < 4; ++r) {
            hcO[     lhi*4 + r][oc] = (_Float16)cc0[r];
            hcO[16 + lhi*4 + r][oc] = (_Float16)cc1[r];
            hcO[32 + lhi*4 + r][oc] = (_Float16)cc2[r];
            hcO[48 + lhi*4 + r][oc] = (_Float16)cc3[r];
        }
        __syncthreads();   // S5: hcO complete
        // ---- export partial, plane-major dense (relaxed sc1 -> MALL) ----
        {
            _Float16* dst = hcP + ((ull)((s*2 + (i&1))*32 + j))*8192 + tid*4;
            #pragma unroll
            for (int k = 0; k < 4; ++k)
                ast64(dst + k*2048, *(const ull*)&hcO[k*16 + pb][pc]);
        }
        __syncthreads();   // S6: all waves' stores drained (vmcnt0 at barrier)
        if (tid == 0) astrlx(flags + blk*64, j + 1);
    }

    // ---- final output: blk 63 (i=31,s=1) sums its partial with blk 62's ----
    if (blk == 63) {
        while (ldrlx(flags + 62*64) < 32) __builtin_amdgcn_s_sleep(1);
        const _Float16* p0 = hcP + ((ull)((0*2 + 1)*32 + 31))*8192 + tid*4;
        #pragma unroll
        for (int k = 0; k < 4; ++k) {
            U64H a; a.u = ald64(p0 + k*2048);
            half4 own = *(const half4*)&hcO[k*16 + pb][pc];
            float* od = out + (k*16 + pb)*128 + pc;
            #pragma unroll
            for (int e = 0; e < 4; ++e) od[e] = (float)a.h[e] + (float)own[e];
        }
    }
}

extern "C" void kernel_launch(void* const* d_in, const int* in_sizes, int n_in,
                              void* d_out, int out_size, void* d_ws, size_t ws_size,
                              hipStream_t stream)
{
    const float* x    = (const float*)d_in[0];
    const float* We   = (const float*)d_in[1];
    const float* be   = (const float*)d_in[2];
    const float* W_ih = (const float*)d_in[3];
    const float* b_ih = (const float*)d_in[4];
    const float* W_hh = (const float*)d_in[5];
    const float* b_hh = (const float*)d_in[6];
    const float* Wc   = (const float*)d_in[7];
    const float* bc   = (const float*)d_in[8];
    char* wsb = (char*)d_ws;
    float* Wx     = (float*)(wsb + OFF_WX);
    _Float16* WtP = (_Float16*)(wsb + OFF_WTP);
    _Float16* WcP = (_Float16*)(wsb + OFF_WCP);
    float* biasG  = (float*)(wsb + OFF_BIASG);
    _Float16* xH  = (_Float16*)(wsb + OFF_XH);
    int* flags    = (int*)(wsb + OFF_FLAGS);
    float* out    = (float*)d_out;

    k_build_wx<<<192, 256, 0, stream>>>(W_ih, We, Wx);
    k_prep_wtp<<<480, 512, 0, stream>>>(Wx, W_hh, WtP);
    k_prep_wcp<<<64, 512, 0, stream>>>(Wc, WcP);
    k_prep_bias<<<4, 256, 0, stream>>>(b_ih, b_hh, W_ih, be, biasG);
    k_prep_x<<<1024, 256, 0, stream>>>(x, xH);
    hipMemsetAsync(flags, 0, 64*64*sizeof(int), stream);
    k_grid<<<64, 512, 0, stream>>>(wsb, bc, out);
}